// Round 4
// baseline (4055.529 us; speedup 1.0000x reference)
//
#include <hip/hip_runtime.h>
#include <math.h>

#define BGRAPH 16
#define NPG    4096
#define NPTS   (BGRAPH*NPG)   // 65536
#define KNN    20
#define NC     40
#define EPSBN  1e-5f
#define SEG    4

typedef _Float16 half8 __attribute__((ext_vector_type(8)));
typedef unsigned long long u64;

// ---------------- ws layout (bytes) ----------------
#define O_X0   0u               // float[NPTS*4]      1 MB
#define O_IDX  1048576u         // int[NPTS*20]       5 MB
#define O_X1   6291456u         // float[NPTS*64]     16 MB
#define O_UV   23068672u        // float[NPTS*256]    64 MB (knn packed partial lists overlay this)
#define O_WT   90177536u        // folded weights + out2enc

// ---------------- helpers ----------------
__device__ __forceinline__ unsigned encf(float v) {
    unsigned u = __float_as_uint(v);
    return (u & 0x80000000u) ? ~u : (u | 0x80000000u);
}
__device__ __forceinline__ float decf(unsigned k) {
    unsigned u = (k & 0x80000000u) ? (k ^ 0x80000000u) : ~k;
    return __uint_as_float(u);
}
// monotone orderable uint from float (handles negatives)
__device__ __forceinline__ unsigned ordf(float f) {
    unsigned u = __float_as_uint(f);
    return u ^ (((unsigned)((int)u >> 31)) | 0x80000000u);
}

// top-20 list as 20 NAMED scalars (never an array -> guaranteed VGPR residency).
// k0 = worst (largest key) ... k19 = best (smallest key). Key = (ordf(d)<<32)|idx.
struct TopK {
    u64 k0,k1,k2,k3,k4,k5,k6,k7,k8,k9,k10,k11,k12,k13,k14,k15,k16,k17,k18,k19;
};
__device__ __forceinline__ void tk_init(TopK& s) {
    s.k0=s.k1=s.k2=s.k3=s.k4=s.k5=s.k6=s.k7=s.k8=s.k9=~0ull;
    s.k10=s.k11=s.k12=s.k13=s.k14=s.k15=s.k16=s.k17=s.k18=s.k19=~0ull;
}
__device__ __forceinline__ void tk_ins(TopK& s, u64 c) {
    bool b0 =c<s.k0;  bool b1 =c<s.k1;  bool b2 =c<s.k2;  bool b3 =c<s.k3;
    bool b4 =c<s.k4;  bool b5 =c<s.k5;  bool b6 =c<s.k6;  bool b7 =c<s.k7;
    bool b8 =c<s.k8;  bool b9 =c<s.k9;  bool b10=c<s.k10; bool b11=c<s.k11;
    bool b12=c<s.k12; bool b13=c<s.k13; bool b14=c<s.k14; bool b15=c<s.k15;
    bool b16=c<s.k16; bool b17=c<s.k17; bool b18=c<s.k18; bool b19=c<s.k19;
    s.k0  = b1  ? s.k1  : (b0  ? c : s.k0);
    s.k1  = b2  ? s.k2  : (b1  ? c : s.k1);
    s.k2  = b3  ? s.k3  : (b2  ? c : s.k2);
    s.k3  = b4  ? s.k4  : (b3  ? c : s.k3);
    s.k4  = b5  ? s.k5  : (b4  ? c : s.k4);
    s.k5  = b6  ? s.k6  : (b5  ? c : s.k5);
    s.k6  = b7  ? s.k7  : (b6  ? c : s.k6);
    s.k7  = b8  ? s.k8  : (b7  ? c : s.k7);
    s.k8  = b9  ? s.k9  : (b8  ? c : s.k8);
    s.k9  = b10 ? s.k10 : (b9  ? c : s.k9);
    s.k10 = b11 ? s.k11 : (b10 ? c : s.k10);
    s.k11 = b12 ? s.k12 : (b11 ? c : s.k11);
    s.k12 = b13 ? s.k13 : (b12 ? c : s.k12);
    s.k13 = b14 ? s.k14 : (b13 ? c : s.k13);
    s.k14 = b15 ? s.k15 : (b14 ? c : s.k14);
    s.k15 = b16 ? s.k16 : (b15 ? c : s.k15);
    s.k16 = b17 ? s.k17 : (b16 ? c : s.k16);
    s.k17 = b18 ? s.k18 : (b17 ? c : s.k17);
    s.k18 = b19 ? s.k19 : (b18 ? c : s.k18);
    s.k19 = b19 ? c : s.k19;
}

// ---------------- K0: fold BN into weights, build Wuv, zero pool accumulators ----------------
__global__ void k_fold(const float* __restrict__ W1, const float* __restrict__ b1,
                       const float* __restrict__ g1, const float* __restrict__ be1,
                       const float* __restrict__ m1, const float* __restrict__ v1,
                       const float* __restrict__ W2, const float* __restrict__ b2,
                       const float* __restrict__ g2, const float* __restrict__ be2,
                       const float* __restrict__ m2, const float* __restrict__ v2,
                       const float* __restrict__ Wc,
                       float* __restrict__ W1f, float* __restrict__ b1f,
                       float* __restrict__ W2f, float* __restrict__ b2f,
                       float* __restrict__ Wuv, unsigned* __restrict__ out2enc)
{
    int t = threadIdx.x;
    for (int i = t; i < 64; i += 256) {
        float s1 = g1[i] * rsqrtf(v1[i] + EPSBN);
        b1f[i] = (b1[i] - m1[i]) * s1 + be1[i];
        float s2 = g2[i] * rsqrtf(v2[i] + EPSBN);
        b2f[i] = (b2[i] - m2[i]) * s2 + be2[i];
    }
    for (int i = t; i < 8*64; i += 256) {
        int c = i & 63;
        W1f[i] = W1[i] * (g1[c] * rsqrtf(v1[c] + EPSBN));
    }
    for (int i = t; i < 64*64; i += 256) {
        int c = i & 63;
        W2f[i] = W2[i] * (g2[c] * rsqrtf(v2[c] + EPSBN));
    }
    for (int i = t; i < 64*256; i += 256) {
        int d = i >> 8, c = i & 255;
        Wuv[i] = (c < 128) ? (Wc[d*128 + c] - Wc[(64+d)*128 + c])
                           : Wc[(64+d)*128 + (c - 128)];
    }
    for (int i = t; i < 16*1024; i += 256) out2enc[i] = 0u;
}

// ---------------- K0b: x0 = [pos | feat] ----------------
__global__ void k_x0(const float* __restrict__ pos, const float* __restrict__ feat,
                     float* __restrict__ x0)
{
    int i = blockIdx.x*256 + threadIdx.x;
    if (i < NPTS) {
        float4 v;
        v.x = pos[i*3+0]; v.y = pos[i*3+1]; v.z = pos[i*3+2]; v.w = feat[i];
        ((float4*)x0)[i] = v;
    }
}

// ---------------- K1a: segmented kNN partials (register-resident branchless top-20) ------
__global__ __launch_bounds__(256) void k_knn_part(const float* __restrict__ x0,
        u64* __restrict__ pk)
{
    __shared__ float4 pts[1024];
    __shared__ float  sqs[1024];
    int x  = blockIdx.x;
    int b  = x >> 6;
    int rb = (x >> 2) & 15;
    int s  = x & 3;
    int t  = threadIdx.x;
    int r  = b*NPG + rb*256 + t;
    float4 xi = ((const float4*)x0)[r];
    float sqi = xi.x*xi.x + xi.y*xi.y + xi.z*xi.z + xi.w*xi.w;
    #pragma unroll
    for (int l = 0; l < 4; ++l) {
        float4 v = ((const float4*)x0)[b*NPG + s*1024 + l*256 + t];
        pts[l*256 + t] = v;
        sqs[l*256 + t] = v.x*v.x + v.y*v.y + v.z*v.z + v.w*v.w;
    }
    __syncthreads();

    TopK ck; tk_init(ck);
    int jbase = b*NPG + s*1024;
    for (int j = 0; j < 1024; ++j) {
        float4 xj = pts[j];
        float dot = xi.x*xj.x + xi.y*xj.y + xi.z*xj.z + xi.w*xj.w;
        float sqj = sqs[j];
        float d = sqi + sqj - 2.0f*dot;
        u64 cand = ((u64)ordf(d) << 32) | (unsigned)(jbase + j);
        tk_ins(ck, cand);
    }
    u64* p = pk + r;
    p[(size_t)(s*KNN+ 0)*NPTS] = ck.k0;  p[(size_t)(s*KNN+ 1)*NPTS] = ck.k1;
    p[(size_t)(s*KNN+ 2)*NPTS] = ck.k2;  p[(size_t)(s*KNN+ 3)*NPTS] = ck.k3;
    p[(size_t)(s*KNN+ 4)*NPTS] = ck.k4;  p[(size_t)(s*KNN+ 5)*NPTS] = ck.k5;
    p[(size_t)(s*KNN+ 6)*NPTS] = ck.k6;  p[(size_t)(s*KNN+ 7)*NPTS] = ck.k7;
    p[(size_t)(s*KNN+ 8)*NPTS] = ck.k8;  p[(size_t)(s*KNN+ 9)*NPTS] = ck.k9;
    p[(size_t)(s*KNN+10)*NPTS] = ck.k10; p[(size_t)(s*KNN+11)*NPTS] = ck.k11;
    p[(size_t)(s*KNN+12)*NPTS] = ck.k12; p[(size_t)(s*KNN+13)*NPTS] = ck.k13;
    p[(size_t)(s*KNN+14)*NPTS] = ck.k14; p[(size_t)(s*KNN+15)*NPTS] = ck.k15;
    p[(size_t)(s*KNN+16)*NPTS] = ck.k16; p[(size_t)(s*KNN+17)*NPTS] = ck.k17;
    p[(size_t)(s*KNN+18)*NPTS] = ck.k18; p[(size_t)(s*KNN+19)*NPTS] = ck.k19;
}

// ---------------- K1b: merge 4 partial lists -> final 20 indices (set only) --------
__global__ __launch_bounds__(256) void k_knn_merge(const u64* __restrict__ pk,
        int* __restrict__ idx)
{
    int r = blockIdx.x*256 + threadIdx.x;
    const u64* p = pk + r;
    TopK ck;
    ck.k0  = p[(size_t) 0*NPTS]; ck.k1  = p[(size_t) 1*NPTS];
    ck.k2  = p[(size_t) 2*NPTS]; ck.k3  = p[(size_t) 3*NPTS];
    ck.k4  = p[(size_t) 4*NPTS]; ck.k5  = p[(size_t) 5*NPTS];
    ck.k6  = p[(size_t) 6*NPTS]; ck.k7  = p[(size_t) 7*NPTS];
    ck.k8  = p[(size_t) 8*NPTS]; ck.k9  = p[(size_t) 9*NPTS];
    ck.k10 = p[(size_t)10*NPTS]; ck.k11 = p[(size_t)11*NPTS];
    ck.k12 = p[(size_t)12*NPTS]; ck.k13 = p[(size_t)13*NPTS];
    ck.k14 = p[(size_t)14*NPTS]; ck.k15 = p[(size_t)15*NPTS];
    ck.k16 = p[(size_t)16*NPTS]; ck.k17 = p[(size_t)17*NPTS];
    ck.k18 = p[(size_t)18*NPTS]; ck.k19 = p[(size_t)19*NPTS];
    #pragma unroll 1
    for (int s = 1; s < SEG; ++s) {
        #pragma unroll 4
        for (int q = 0; q < KNN; ++q) {
            u64 cand = p[(size_t)(s*KNN + q)*NPTS];
            tk_ins(ck, cand);
        }
    }
    int* o = idx + (size_t)r*KNN;
    o[0]=(int)(unsigned)ck.k0;   o[1]=(int)(unsigned)ck.k1;
    o[2]=(int)(unsigned)ck.k2;   o[3]=(int)(unsigned)ck.k3;
    o[4]=(int)(unsigned)ck.k4;   o[5]=(int)(unsigned)ck.k5;
    o[6]=(int)(unsigned)ck.k6;   o[7]=(int)(unsigned)ck.k7;
    o[8]=(int)(unsigned)ck.k8;   o[9]=(int)(unsigned)ck.k9;
    o[10]=(int)(unsigned)ck.k10; o[11]=(int)(unsigned)ck.k11;
    o[12]=(int)(unsigned)ck.k12; o[13]=(int)(unsigned)ck.k13;
    o[14]=(int)(unsigned)ck.k14; o[15]=(int)(unsigned)ck.k15;
    o[16]=(int)(unsigned)ck.k16; o[17]=(int)(unsigned)ck.k17;
    o[18]=(int)(unsigned)ck.k18; o[19]=(int)(unsigned)ck.k19;
}

// ---------------- K2: EdgeConv1, one wave per block, fp16 LDS staging ----------------
#define PTS 16
__global__ __launch_bounds__(64) void k_conv1(const float* __restrict__ x0, const int* __restrict__ idx,
        const float* __restrict__ W1f, const float* __restrict__ b1f,
        const float* __restrict__ W2f, const float* __restrict__ b2f,
        const float* __restrict__ W3,  const float* __restrict__ b3,
        float* __restrict__ x1)
{
    __shared__ _Float16 hs0[20*64];
    __shared__ _Float16 hs1[20*64];
    int c = threadIdx.x;
    float w1c[8], w2c[64], w3c[64];
    #pragma unroll
    for (int f = 0; f < 8; ++f)  w1c[f] = W1f[f*64 + c];
    #pragma unroll
    for (int d = 0; d < 64; ++d) w2c[d] = W2f[d*64 + c];
    #pragma unroll
    for (int d = 0; d < 64; ++d) w3c[d] = W3[d*64 + c];
    float b1c = b1f[c], b2c = b2f[c], b3c = b3[c];

    #pragma unroll 1
    for (int pp = 0; pp < PTS; ++pp) {
        int i = blockIdx.x*PTS + pp;
        float4 xi = ((const float4*)x0)[i];
        #pragma unroll 4
        for (int k = 0; k < KNN; ++k) {
            int j = idx[i*KNN + k];
            float4 xj = ((const float4*)x0)[j];
            float h = b1c + xi.x*w1c[0] + xi.y*w1c[1] + xi.z*w1c[2] + xi.w*w1c[3]
                          + (xj.x-xi.x)*w1c[4] + (xj.y-xi.y)*w1c[5]
                          + (xj.z-xi.z)*w1c[6] + (xj.w-xi.w)*w1c[7];
            hs0[k*64 + c] = (_Float16)fmaxf(h, 0.0f);
        }
        __syncthreads();
        #pragma unroll 1
        for (int kc = 0; kc < 4; ++kc) {
            float acc[5];
            #pragma unroll
            for (int k5 = 0; k5 < 5; ++k5) acc[k5] = b2c;
            #pragma unroll
            for (int q = 0; q < 8; ++q) {
                #pragma unroll
                for (int k5 = 0; k5 < 5; ++k5) {
                    half8 hv = *(const half8*)&hs0[(kc*5 + k5)*64 + q*8];
                    #pragma unroll
                    for (int jj = 0; jj < 8; ++jj)
                        acc[k5] = fmaf((float)hv[jj], w2c[q*8 + jj], acc[k5]);
                }
            }
            #pragma unroll
            for (int k5 = 0; k5 < 5; ++k5)
                hs1[(kc*5 + k5)*64 + c] = (_Float16)fmaxf(acc[k5], 0.0f);
        }
        __syncthreads();
        float mx = -3.0e38f;
        #pragma unroll 1
        for (int kc = 0; kc < 4; ++kc) {
            float acc[5];
            #pragma unroll
            for (int k5 = 0; k5 < 5; ++k5) acc[k5] = b3c;
            #pragma unroll
            for (int q = 0; q < 8; ++q) {
                #pragma unroll
                for (int k5 = 0; k5 < 5; ++k5) {
                    half8 hv = *(const half8*)&hs1[(kc*5 + k5)*64 + q*8];
                    #pragma unroll
                    for (int jj = 0; jj < 8; ++jj)
                        acc[k5] = fmaf((float)hv[jj], w3c[q*8 + jj], acc[k5]);
                }
            }
            #pragma unroll
            for (int k5 = 0; k5 < 5; ++k5) mx = fmaxf(mx, acc[k5]);
        }
        x1[(size_t)i*64 + c] = mx;
        __syncthreads();
    }
}

// ---------------- K3: uv = x1 @ [Wu | Wv]  (u' gets +bc) ----------------
__global__ __launch_bounds__(256) void k_uv(const float* __restrict__ x1, const float* __restrict__ Wuv,
                                            const float* __restrict__ bc, float* __restrict__ uv)
{
    __shared__ float4 As[64*16];  // 64 rows x 64 cols of x1
    int m0 = blockIdx.x * 64;
    int t  = threadIdx.x;
    #pragma unroll
    for (int l = 0; l < 4; ++l) {
        int lin = l*256 + t;  // 0..1023
        As[lin] = ((const float4*)x1)[(size_t)m0*16 + lin];
    }
    __syncthreads();
    int c = t;  // 0..255
    float acc[64];
    #pragma unroll
    for (int p = 0; p < 64; ++p) acc[p] = 0.f;
    for (int dq = 0; dq < 16; ++dq) {
        float bv0 = Wuv[(dq*4+0)*256 + c];
        float bv1 = Wuv[(dq*4+1)*256 + c];
        float bv2 = Wuv[(dq*4+2)*256 + c];
        float bv3 = Wuv[(dq*4+3)*256 + c];
        #pragma unroll
        for (int p = 0; p < 64; ++p) {
            float4 a = As[p*16 + dq];
            acc[p] += a.x*bv0 + a.y*bv1 + a.z*bv2 + a.w*bv3;
        }
    }
    float badd = (c < 128) ? bc[c] : 0.0f;
    #pragma unroll
    for (int p = 0; p < 64; ++p)
        uv[(size_t)(m0+p)*256 + c] = acc[p] + badd;
}

// ---------------- K4: x2 = u' + max_k v[nbr]  (in-place into u' half of uv) ----------------
__global__ __launch_bounds__(256) void k_x2(const int* __restrict__ idx, float* __restrict__ uv)
{
    int p = blockIdx.x*2 + (threadIdx.x >> 7);
    int c = threadIdx.x & 127;
    float m = -3.0e38f;
    #pragma unroll
    for (int k = 0; k < KNN; ++k) {
        int j = idx[p*KNN + k];
        m = fmaxf(m, uv[(size_t)j*256 + 128 + c]);
    }
    uv[(size_t)p*256 + c] += m;
}

// ---------------- K5: out1 = [x1|x2] @ Wl (+bl), fused per-graph max-pool via atomicMax ----------------
__global__ __launch_bounds__(256) void k_out1(const float* __restrict__ x1, const float* __restrict__ uv,
        const float* __restrict__ Wl, const float* __restrict__ bl, unsigned* __restrict__ out2enc)
{
    __shared__ float As[64][68];
    __shared__ float Bs[64][128];
    int n0 = blockIdx.x * 128;   // 8 col-blocks
    int m0 = blockIdx.y * 64;    // 1024 row-blocks (graph-aligned: 64 | 4096)
    int t  = threadIdx.x;
    int tx = t & 15, ty = t >> 4;
    float acc[4][8];
    #pragma unroll
    for (int i = 0; i < 4; ++i)
        #pragma unroll
        for (int j = 0; j < 8; ++j) acc[i][j] = 0.f;

    for (int kc = 0; kc < 3; ++kc) {
        __syncthreads();
        {
            const float* src = (kc == 0) ? (x1 + (size_t)m0*64) : (uv + (size_t)m0*256 + (kc-1)*64);
            int sstride = (kc == 0) ? 64 : 256;
            #pragma unroll
            for (int l = 0; l < 4; ++l) {
                int lin = l*256 + t;           // 0..1023
                int row = lin >> 4, q = lin & 15;
                float4 v = *(const float4*)(src + (size_t)row*sstride + q*4);
                As[row][q*4+0] = v.x; As[row][q*4+1] = v.y;
                As[row][q*4+2] = v.z; As[row][q*4+3] = v.w;
            }
        }
        #pragma unroll
        for (int l = 0; l < 8; ++l) {
            int lin = l*256 + t;               // 0..2047
            int row = lin >> 5, q = lin & 31;
            float4 v = *(const float4*)(Wl + (size_t)(kc*64 + row)*1024 + n0 + q*4);
            *(float4*)&Bs[row][q*4] = v;
        }
        __syncthreads();
        #pragma unroll 8
        for (int kk = 0; kk < 64; ++kk) {
            float a[4], bvs[8];
            #pragma unroll
            for (int i = 0; i < 4; ++i) a[i] = As[ty*4+i][kk];
            #pragma unroll
            for (int j = 0; j < 8; ++j) bvs[j] = Bs[kk][tx*8+j];
            #pragma unroll
            for (int i = 0; i < 4; ++i)
                #pragma unroll
                for (int j = 0; j < 8; ++j) acc[i][j] += a[i]*bvs[j];
        }
    }
    float cm[8];
    #pragma unroll
    for (int j = 0; j < 8; ++j) {
        float m = acc[0][j];
        #pragma unroll
        for (int i = 1; i < 4; ++i) m = fmaxf(m, acc[i][j]);
        cm[j] = m + bl[n0 + tx*8 + j];
    }
    __syncthreads();
    float* red = &As[0][0];  // reuse: [16][128]
    #pragma unroll
    for (int j = 0; j < 8; ++j) red[ty*128 + tx*8 + j] = cm[j];
    __syncthreads();
    if (ty == 0) {
        int g = m0 >> 12;  // graph id
        #pragma unroll
        for (int j = 0; j < 8; ++j) {
            int cc = tx*8 + j;
            float m = red[cc];
            #pragma unroll
            for (int r2 = 1; r2 < 16; ++r2) m = fmaxf(m, red[r2*128 + cc]);
            atomicMax(&out2enc[g*1024 + n0 + cc], encf(m));
        }
    }
}

// ---------------- K6: per-graph head MLP + log_softmax ----------------
__global__ __launch_bounds__(256) void k_head(const unsigned* __restrict__ out2enc,
        const float* __restrict__ Wa, const float* __restrict__ ba,
        const float* __restrict__ Wb, const float* __restrict__ bb,
        const float* __restrict__ Wo, const float* __restrict__ bo,
        float* __restrict__ out)
{
    __shared__ float s1[1024];
    __shared__ float s2[512];
    __shared__ float s3[256];
    __shared__ float sl[NC];
    int g = blockIdx.x, t = threadIdx.x;
    for (int i = t; i < 1024; i += 256) s1[i] = decf(out2enc[g*1024 + i]);
    __syncthreads();
    for (int cc = t; cc < 512; cc += 256) {
        float a = ba[cc];
        #pragma unroll 8
        for (int d = 0; d < 1024; ++d) a += s1[d] * Wa[(size_t)d*512 + cc];
        s2[cc] = fmaxf(a, 0.f);
    }
    __syncthreads();
    if (t < 256) {
        float a = bb[t];
        #pragma unroll 8
        for (int d = 0; d < 512; ++d) a += s2[d] * Wb[(size_t)d*256 + t];
        s3[t] = fmaxf(a, 0.f);
    }
    __syncthreads();
    if (t < NC) {
        float a = bo[t];
        #pragma unroll 8
        for (int d = 0; d < 256; ++d) a += s3[d] * Wo[d*NC + t];
        sl[t] = a;
    }
    __syncthreads();
    if (t < 64) {
        float v = (t < NC) ? sl[t] : -3.0e38f;
        float m = v;
        #pragma unroll
        for (int o2 = 32; o2 >= 1; o2 >>= 1) m = fmaxf(m, __shfl_xor(m, o2));
        float e = (t < NC) ? expf(sl[t] - m) : 0.f;
        float s = e;
        #pragma unroll
        for (int o2 = 32; o2 >= 1; o2 >>= 1) s += __shfl_xor(s, o2);
        float ls = logf(s) + m;
        if (t < NC) out[g*NC + t] = sl[t] - ls;
    }
}

// ---------------- launch ----------------
extern "C" void kernel_launch(void* const* d_in, const int* in_sizes, int n_in,
                              void* d_out, int out_size, void* d_ws, size_t ws_size,
                              hipStream_t stream)
{
    const float* pos  = (const float*)d_in[0];
    const float* feat = (const float*)d_in[1];
    const float* W1 = (const float*)d_in[2];
    const float* b1 = (const float*)d_in[3];
    const float* g1 = (const float*)d_in[4];
    const float* be1= (const float*)d_in[5];
    const float* m1 = (const float*)d_in[6];
    const float* v1 = (const float*)d_in[7];
    const float* W2 = (const float*)d_in[8];
    const float* b2 = (const float*)d_in[9];
    const float* g2 = (const float*)d_in[10];
    const float* be2= (const float*)d_in[11];
    const float* m2 = (const float*)d_in[12];
    const float* v2 = (const float*)d_in[13];
    const float* W3 = (const float*)d_in[14];
    const float* b3 = (const float*)d_in[15];
    const float* Wc = (const float*)d_in[16];
    const float* bc = (const float*)d_in[17];
    const float* Wl = (const float*)d_in[18];
    const float* bl = (const float*)d_in[19];
    const float* Wa = (const float*)d_in[20];
    const float* ba = (const float*)d_in[21];
    const float* Wb = (const float*)d_in[22];
    const float* bb = (const float*)d_in[23];
    const float* Wo = (const float*)d_in[24];
    const float* bo = (const float*)d_in[25];
    float* out = (float*)d_out;

    char* ws = (char*)d_ws;
    float* x0  = (float*)(ws + O_X0);
    int*   idx = (int*)  (ws + O_IDX);
    float* x1  = (float*)(ws + O_X1);
    float* uv  = (float*)(ws + O_UV);
    u64*   pk  = (u64*)  (ws + O_UV);   // packed knn partials overlay uv (dead until k_uv)
    float* W1f = (float*)(ws + O_WT);
    float* b1f = W1f + 512;
    float* W2f = b1f + 64;
    float* b2f = W2f + 4096;
    float* Wuv = b2f + 64;
    unsigned* out2enc = (unsigned*)(Wuv + 64*256);

    k_fold <<<1, 256, 0, stream>>>(W1,b1,g1,be1,m1,v1, W2,b2,g2,be2,m2,v2, Wc,
                                   W1f,b1f,W2f,b2f,Wuv,out2enc);
    k_x0   <<<NPTS/256, 256, 0, stream>>>(pos, feat, x0);
    k_knn_part <<<BGRAPH*16*SEG, 256, 0, stream>>>(x0, pk);
    k_knn_merge<<<NPTS/256, 256, 0, stream>>>(pk, idx);
    k_conv1<<<NPTS/PTS, 64, 0, stream>>>(x0, idx, W1f, b1f, W2f, b2f, W3, b3, x1);
    k_uv   <<<NPTS/64, 256, 0, stream>>>(x1, Wuv, bc, uv);
    k_x2   <<<NPTS/2, 256, 0, stream>>>(idx, uv);
    dim3 g5(8, 1024);
    k_out1 <<<g5, 256, 0, stream>>>(x1, uv, Wl, bl, out2enc);
    k_head <<<BGRAPH, 256, 0, stream>>>(out2enc, Wa,ba,Wb,bb,Wo,bo, out);
}

// Round 5
// 1890.413 us; speedup vs baseline: 2.1453x; 2.1453x over previous
//
#include <hip/hip_runtime.h>
#include <math.h>

#define BGRAPH 16
#define NPG    4096
#define NPTS   (BGRAPH*NPG)   // 65536
#define KNN    20
#define NC     40
#define EPSBN  1e-5f
#define SEG    4
#define BIGF   3.0e38f

typedef _Float16 half8 __attribute__((ext_vector_type(8)));
typedef unsigned long long u64;

// ---------------- ws layout (bytes) ----------------
#define O_X0   0u               // float[NPTS*4]      1 MB
#define O_IDX  1048576u         // int[NPTS*20]       5 MB
#define O_X1   6291456u         // float[NPTS*64]     16 MB
#define O_UV   23068672u        // float[NPTS*256]    64 MB (knn packed partial lists overlay this)
#define O_WT   90177536u        // folded weights + out2enc

// ---------------- helpers ----------------
__device__ __forceinline__ unsigned encf(float v) {
    unsigned u = __float_as_uint(v);
    return (u & 0x80000000u) ? ~u : (u | 0x80000000u);
}
__device__ __forceinline__ float decf(unsigned k) {
    unsigned u = (k & 0x80000000u) ? (k ^ 0x80000000u) : ~k;
    return __uint_as_float(u);
}
// deterministic distance: identical instruction sequence at every use site
__device__ __forceinline__ float distf(float4 xi, float sqi, float4 xj, float sqj) {
    float dot = xi.x * xj.x;
    dot = fmaf(xi.y, xj.y, dot);
    dot = fmaf(xi.z, xj.z, dot);
    dot = fmaf(xi.w, xj.w, dot);
    return fmaf(-2.0f, dot, sqi + sqj);
}

// 20-slot branchless compare-exchange insert (f32 values only), f0=worst .. f19=best
#define TK_DECL float f0=BIGF,f1=BIGF,f2=BIGF,f3=BIGF,f4=BIGF,f5=BIGF,f6=BIGF,f7=BIGF,f8=BIGF,f9=BIGF, \
                     f10=BIGF,f11=BIGF,f12=BIGF,f13=BIGF,f14=BIGF,f15=BIGF,f16=BIGF,f17=BIGF,f18=BIGF,f19=BIGF;
#define TK_STEP(S) t2 = fminf(S, c); c = fmaxf(S, c); S = t2;
#define TK_INSERT(dv) { float c = (dv), t2; \
    TK_STEP(f19) TK_STEP(f18) TK_STEP(f17) TK_STEP(f16) TK_STEP(f15) \
    TK_STEP(f14) TK_STEP(f13) TK_STEP(f12) TK_STEP(f11) TK_STEP(f10) \
    TK_STEP(f9)  TK_STEP(f8)  TK_STEP(f7)  TK_STEP(f6)  TK_STEP(f5)  \
    TK_STEP(f4)  TK_STEP(f3)  TK_STEP(f2)  TK_STEP(f1)  TK_STEP(f0)  }

// ---------------- K0: fold BN into weights, build Wuv, zero pool accumulators ----------------
__global__ void k_fold(const float* __restrict__ W1, const float* __restrict__ b1,
                       const float* __restrict__ g1, const float* __restrict__ be1,
                       const float* __restrict__ m1, const float* __restrict__ v1,
                       const float* __restrict__ W2, const float* __restrict__ b2,
                       const float* __restrict__ g2, const float* __restrict__ be2,
                       const float* __restrict__ m2, const float* __restrict__ v2,
                       const float* __restrict__ Wc,
                       float* __restrict__ W1f, float* __restrict__ b1f,
                       float* __restrict__ W2f, float* __restrict__ b2f,
                       float* __restrict__ Wuv, unsigned* __restrict__ out2enc)
{
    int t = threadIdx.x;
    for (int i = t; i < 64; i += 256) {
        float s1 = g1[i] * rsqrtf(v1[i] + EPSBN);
        b1f[i] = (b1[i] - m1[i]) * s1 + be1[i];
        float s2 = g2[i] * rsqrtf(v2[i] + EPSBN);
        b2f[i] = (b2[i] - m2[i]) * s2 + be2[i];
    }
    for (int i = t; i < 8*64; i += 256) {
        int c = i & 63;
        W1f[i] = W1[i] * (g1[c] * rsqrtf(v1[c] + EPSBN));
    }
    for (int i = t; i < 64*64; i += 256) {
        int c = i & 63;
        W2f[i] = W2[i] * (g2[c] * rsqrtf(v2[c] + EPSBN));
    }
    for (int i = t; i < 64*256; i += 256) {
        int d = i >> 8, c = i & 255;
        Wuv[i] = (c < 128) ? (Wc[d*128 + c] - Wc[(64+d)*128 + c])
                           : Wc[(64+d)*128 + (c - 128)];
    }
    for (int i = t; i < 16*1024; i += 256) out2enc[i] = 0u;
}

// ---------------- K0b: x0 = [pos | feat] ----------------
__global__ void k_x0(const float* __restrict__ pos, const float* __restrict__ feat,
                     float* __restrict__ x0)
{
    int i = blockIdx.x*256 + threadIdx.x;
    if (i < NPTS) {
        float4 v;
        v.x = pos[i*3+0]; v.y = pos[i*3+1]; v.z = pos[i*3+2]; v.w = feat[i];
        ((float4*)x0)[i] = v;
    }
}

// ---------------- K1a: segmented kNN partials (f32 value-phase + index recovery) ----------
// Phase 1: top-20 distance VALUES only (20 named f32 -> ~45 VGPR total, fits RA budget).
// Phase 2: rescan with bit-identical distf; write (d,idx) keys: strict-< first, ==tau fill.
__global__ __launch_bounds__(256) void k_knn_part(const float* __restrict__ x0,
        u64* __restrict__ pk)
{
    __shared__ float4 pts[1024];
    __shared__ float  sqs[1024];
    int x  = blockIdx.x;
    int b  = x >> 6;
    int rb = (x >> 2) & 15;
    int s  = x & 3;
    int t  = threadIdx.x;
    int r  = b*NPG + rb*256 + t;
    float4 xi = ((const float4*)x0)[r];
    float sqi = xi.x*xi.x + xi.y*xi.y + xi.z*xi.z + xi.w*xi.w;
    #pragma unroll
    for (int l = 0; l < 4; ++l) {
        float4 v = ((const float4*)x0)[b*NPG + s*1024 + l*256 + t];
        pts[l*256 + t] = v;
        sqs[l*256 + t] = v.x*v.x + v.y*v.y + v.z*v.z + v.w*v.w;
    }
    __syncthreads();

    TK_DECL
    for (int j = 0; j < 1024; ++j) {
        float d = distf(xi, sqi, pts[j], sqs[j]);
        TK_INSERT(d)
    }
    float tau = f0;   // 20th smallest value in this segment

    int jbase = b*NPG + s*1024;
    u64* pcol = pk + (size_t)s*KNN*NPTS + r;
    unsigned cnt = 0;
    // pass 2a: strictly smaller than tau (at most 19 of these)
    for (int j = 0; j < 1024; ++j) {
        float d = distf(xi, sqi, pts[j], sqs[j]);
        if (d < tau && cnt < KNN) {
            pcol[(size_t)cnt*NPTS] = ((u64)__float_as_uint(d) << 32) | (unsigned)(jbase + j);
            cnt++;
        }
    }
    // pass 2b: equal to tau, in increasing index order, fill to 20
    for (int j = 0; j < 1024; ++j) {
        float d = distf(xi, sqi, pts[j], sqs[j]);
        if (d == tau && cnt < KNN) {
            pcol[(size_t)cnt*NPTS] = ((u64)__float_as_uint(tau) << 32) | (unsigned)(jbase + j);
            cnt++;
        }
    }
    // defensive fill (unreachable in practice): +inf keys, never win the merge
    while (cnt < KNN) {
        pcol[(size_t)cnt*NPTS] = ((u64)0x7F800000u << 32) | (unsigned)r;
        cnt++;
    }
}

// ---------------- K1b: merge 4 partial lists -> final 20 indices (set only) --------
__global__ __launch_bounds__(256) void k_knn_merge(const u64* __restrict__ pk,
        int* __restrict__ idx)
{
    int r = blockIdx.x*256 + threadIdx.x;
    const unsigned* ph = (const unsigned*)pk;   // hi word of slot q at ((q*NPTS + r)*2 + 1)

    TK_DECL
    for (int q = 0; q < SEG*KNN; ++q) {
        float du = __uint_as_float(ph[((size_t)q*NPTS + r)*2 + 1]);
        TK_INSERT(du)
    }
    float tau = f0;   // 20th smallest distance overall

    unsigned cnt = 0;
    int* o = idx + (size_t)r*KNN;
    for (int q = 0; q < SEG*KNN; ++q) {
        u64 key = pk[(size_t)q*NPTS + r];
        float du = __uint_as_float((unsigned)(key >> 32));
        if (du < tau && cnt < KNN) { o[cnt] = (int)(unsigned)key; cnt++; }
    }
    for (int q = 0; q < SEG*KNN; ++q) {
        u64 key = pk[(size_t)q*NPTS + r];
        float du = __uint_as_float((unsigned)(key >> 32));
        if (du == tau && cnt < KNN) { o[cnt] = (int)(unsigned)key; cnt++; }
    }
    while (cnt < KNN) { o[cnt] = r; cnt++; }
}

// ---------------- K2: EdgeConv1, one wave per block, fp16 LDS staging ----------------
#define PTS 16
__global__ __launch_bounds__(64) void k_conv1(const float* __restrict__ x0, const int* __restrict__ idx,
        const float* __restrict__ W1f, const float* __restrict__ b1f,
        const float* __restrict__ W2f, const float* __restrict__ b2f,
        const float* __restrict__ W3,  const float* __restrict__ b3,
        float* __restrict__ x1)
{
    __shared__ _Float16 hs0[20*64];
    __shared__ _Float16 hs1[20*64];
    int c = threadIdx.x;
    float w1c[8], w2c[64], w3c[64];
    #pragma unroll
    for (int f = 0; f < 8; ++f)  w1c[f] = W1f[f*64 + c];
    #pragma unroll
    for (int d = 0; d < 64; ++d) w2c[d] = W2f[d*64 + c];
    #pragma unroll
    for (int d = 0; d < 64; ++d) w3c[d] = W3[d*64 + c];
    float b1c = b1f[c], b2c = b2f[c], b3c = b3[c];

    #pragma unroll 1
    for (int pp = 0; pp < PTS; ++pp) {
        int i = blockIdx.x*PTS + pp;
        float4 xi = ((const float4*)x0)[i];
        #pragma unroll 4
        for (int k = 0; k < KNN; ++k) {
            int j = idx[i*KNN + k];
            float4 xj = ((const float4*)x0)[j];
            float h = b1c + xi.x*w1c[0] + xi.y*w1c[1] + xi.z*w1c[2] + xi.w*w1c[3]
                          + (xj.x-xi.x)*w1c[4] + (xj.y-xi.y)*w1c[5]
                          + (xj.z-xi.z)*w1c[6] + (xj.w-xi.w)*w1c[7];
            hs0[k*64 + c] = (_Float16)fmaxf(h, 0.0f);
        }
        __syncthreads();
        #pragma unroll 1
        for (int kc = 0; kc < 4; ++kc) {
            float acc[5];
            #pragma unroll
            for (int k5 = 0; k5 < 5; ++k5) acc[k5] = b2c;
            #pragma unroll
            for (int q = 0; q < 8; ++q) {
                #pragma unroll
                for (int k5 = 0; k5 < 5; ++k5) {
                    half8 hv = *(const half8*)&hs0[(kc*5 + k5)*64 + q*8];
                    #pragma unroll
                    for (int jj = 0; jj < 8; ++jj)
                        acc[k5] = fmaf((float)hv[jj], w2c[q*8 + jj], acc[k5]);
                }
            }
            #pragma unroll
            for (int k5 = 0; k5 < 5; ++k5)
                hs1[(kc*5 + k5)*64 + c] = (_Float16)fmaxf(acc[k5], 0.0f);
        }
        __syncthreads();
        float mx = -3.0e38f;
        #pragma unroll 1
        for (int kc = 0; kc < 4; ++kc) {
            float acc[5];
            #pragma unroll
            for (int k5 = 0; k5 < 5; ++k5) acc[k5] = b3c;
            #pragma unroll
            for (int q = 0; q < 8; ++q) {
                #pragma unroll
                for (int k5 = 0; k5 < 5; ++k5) {
                    half8 hv = *(const half8*)&hs1[(kc*5 + k5)*64 + q*8];
                    #pragma unroll
                    for (int jj = 0; jj < 8; ++jj)
                        acc[k5] = fmaf((float)hv[jj], w3c[q*8 + jj], acc[k5]);
                }
            }
            #pragma unroll
            for (int k5 = 0; k5 < 5; ++k5) mx = fmaxf(mx, acc[k5]);
        }
        x1[(size_t)i*64 + c] = mx;
        __syncthreads();
    }
}

// ---------------- K3: uv = x1 @ [Wu | Wv]  (u' gets +bc) ----------------
__global__ __launch_bounds__(256) void k_uv(const float* __restrict__ x1, const float* __restrict__ Wuv,
                                            const float* __restrict__ bc, float* __restrict__ uv)
{
    __shared__ float4 As[64*16];  // 64 rows x 64 cols of x1
    int m0 = blockIdx.x * 64;
    int t  = threadIdx.x;
    #pragma unroll
    for (int l = 0; l < 4; ++l) {
        int lin = l*256 + t;  // 0..1023
        As[lin] = ((const float4*)x1)[(size_t)m0*16 + lin];
    }
    __syncthreads();
    int c = t;  // 0..255
    float acc[64];
    #pragma unroll
    for (int p = 0; p < 64; ++p) acc[p] = 0.f;
    for (int dq = 0; dq < 16; ++dq) {
        float bv0 = Wuv[(dq*4+0)*256 + c];
        float bv1 = Wuv[(dq*4+1)*256 + c];
        float bv2 = Wuv[(dq*4+2)*256 + c];
        float bv3 = Wuv[(dq*4+3)*256 + c];
        #pragma unroll
        for (int p = 0; p < 64; ++p) {
            float4 a = As[p*16 + dq];
            acc[p] += a.x*bv0 + a.y*bv1 + a.z*bv2 + a.w*bv3;
        }
    }
    float badd = (c < 128) ? bc[c] : 0.0f;
    #pragma unroll
    for (int p = 0; p < 64; ++p)
        uv[(size_t)(m0+p)*256 + c] = acc[p] + badd;
}

// ---------------- K4: x2 = u' + max_k v[nbr]  (in-place into u' half of uv) ----------------
__global__ __launch_bounds__(256) void k_x2(const int* __restrict__ idx, float* __restrict__ uv)
{
    int p = blockIdx.x*2 + (threadIdx.x >> 7);
    int c = threadIdx.x & 127;
    float m = -3.0e38f;
    #pragma unroll
    for (int k = 0; k < KNN; ++k) {
        int j = idx[p*KNN + k];
        m = fmaxf(m, uv[(size_t)j*256 + 128 + c]);
    }
    uv[(size_t)p*256 + c] += m;
}

// ---------------- K5: out1 = [x1|x2] @ Wl (+bl), fused per-graph max-pool via atomicMax ----------------
__global__ __launch_bounds__(256) void k_out1(const float* __restrict__ x1, const float* __restrict__ uv,
        const float* __restrict__ Wl, const float* __restrict__ bl, unsigned* __restrict__ out2enc)
{
    __shared__ float As[64][68];
    __shared__ float Bs[64][128];
    int n0 = blockIdx.x * 128;   // 8 col-blocks
    int m0 = blockIdx.y * 64;    // 1024 row-blocks (graph-aligned: 64 | 4096)
    int t  = threadIdx.x;
    int tx = t & 15, ty = t >> 4;
    float acc[4][8];
    #pragma unroll
    for (int i = 0; i < 4; ++i)
        #pragma unroll
        for (int j = 0; j < 8; ++j) acc[i][j] = 0.f;

    for (int kc = 0; kc < 3; ++kc) {
        __syncthreads();
        {
            const float* src = (kc == 0) ? (x1 + (size_t)m0*64) : (uv + (size_t)m0*256 + (kc-1)*64);
            int sstride = (kc == 0) ? 64 : 256;
            #pragma unroll
            for (int l = 0; l < 4; ++l) {
                int lin = l*256 + t;           // 0..1023
                int row = lin >> 4, q = lin & 15;
                float4 v = *(const float4*)(src + (size_t)row*sstride + q*4);
                As[row][q*4+0] = v.x; As[row][q*4+1] = v.y;
                As[row][q*4+2] = v.z; As[row][q*4+3] = v.w;
            }
        }
        #pragma unroll
        for (int l = 0; l < 8; ++l) {
            int lin = l*256 + t;               // 0..2047
            int row = lin >> 5, q = lin & 31;
            float4 v = *(const float4*)(Wl + (size_t)(kc*64 + row)*1024 + n0 + q*4);
            *(float4*)&Bs[row][q*4] = v;
        }
        __syncthreads();
        #pragma unroll 8
        for (int kk = 0; kk < 64; ++kk) {
            float a[4], bvs[8];
            #pragma unroll
            for (int i = 0; i < 4; ++i) a[i] = As[ty*4+i][kk];
            #pragma unroll
            for (int j = 0; j < 8; ++j) bvs[j] = Bs[kk][tx*8+j];
            #pragma unroll
            for (int i = 0; i < 4; ++i)
                #pragma unroll
                for (int j = 0; j < 8; ++j) acc[i][j] += a[i]*bvs[j];
        }
    }
    float cm[8];
    #pragma unroll
    for (int j = 0; j < 8; ++j) {
        float m = acc[0][j];
        #pragma unroll
        for (int i = 1; i < 4; ++i) m = fmaxf(m, acc[i][j]);
        cm[j] = m + bl[n0 + tx*8 + j];
    }
    __syncthreads();
    float* red = &As[0][0];  // reuse: [16][128]
    #pragma unroll
    for (int j = 0; j < 8; ++j) red[ty*128 + tx*8 + j] = cm[j];
    __syncthreads();
    if (ty == 0) {
        int g = m0 >> 12;  // graph id
        #pragma unroll
        for (int j = 0; j < 8; ++j) {
            int cc = tx*8 + j;
            float m = red[cc];
            #pragma unroll
            for (int r2 = 1; r2 < 16; ++r2) m = fmaxf(m, red[r2*128 + cc]);
            atomicMax(&out2enc[g*1024 + n0 + cc], encf(m));
        }
    }
}

// ---------------- K6: per-graph head MLP + log_softmax ----------------
__global__ __launch_bounds__(256) void k_head(const unsigned* __restrict__ out2enc,
        const float* __restrict__ Wa, const float* __restrict__ ba,
        const float* __restrict__ Wb, const float* __restrict__ bb,
        const float* __restrict__ Wo, const float* __restrict__ bo,
        float* __restrict__ out)
{
    __shared__ float s1[1024];
    __shared__ float s2[512];
    __shared__ float s3[256];
    __shared__ float sl[NC];
    int g = blockIdx.x, t = threadIdx.x;
    for (int i = t; i < 1024; i += 256) s1[i] = decf(out2enc[g*1024 + i]);
    __syncthreads();
    for (int cc = t; cc < 512; cc += 256) {
        float a = ba[cc];
        #pragma unroll 8
        for (int d = 0; d < 1024; ++d) a += s1[d] * Wa[(size_t)d*512 + cc];
        s2[cc] = fmaxf(a, 0.f);
    }
    __syncthreads();
    if (t < 256) {
        float a = bb[t];
        #pragma unroll 8
        for (int d = 0; d < 512; ++d) a += s2[d] * Wb[(size_t)d*256 + t];
        s3[t] = fmaxf(a, 0.f);
    }
    __syncthreads();
    if (t < NC) {
        float a = bo[t];
        #pragma unroll 8
        for (int d = 0; d < 256; ++d) a += s3[d] * Wo[d*NC + t];
        sl[t] = a;
    }
    __syncthreads();
    if (t < 64) {
        float v = (t < NC) ? sl[t] : -3.0e38f;
        float m = v;
        #pragma unroll
        for (int o2 = 32; o2 >= 1; o2 >>= 1) m = fmaxf(m, __shfl_xor(m, o2));
        float e = (t < NC) ? expf(sl[t] - m) : 0.f;
        float s = e;
        #pragma unroll
        for (int o2 = 32; o2 >= 1; o2 >>= 1) s += __shfl_xor(s, o2);
        float ls = logf(s) + m;
        if (t < NC) out[g*NC + t] = sl[t] - ls;
    }
}

// ---------------- launch ----------------
extern "C" void kernel_launch(void* const* d_in, const int* in_sizes, int n_in,
                              void* d_out, int out_size, void* d_ws, size_t ws_size,
                              hipStream_t stream)
{
    const float* pos  = (const float*)d_in[0];
    const float* feat = (const float*)d_in[1];
    const float* W1 = (const float*)d_in[2];
    const float* b1 = (const float*)d_in[3];
    const float* g1 = (const float*)d_in[4];
    const float* be1= (const float*)d_in[5];
    const float* m1 = (const float*)d_in[6];
    const float* v1 = (const float*)d_in[7];
    const float* W2 = (const float*)d_in[8];
    const float* b2 = (const float*)d_in[9];
    const float* g2 = (const float*)d_in[10];
    const float* be2= (const float*)d_in[11];
    const float* m2 = (const float*)d_in[12];
    const float* v2 = (const float*)d_in[13];
    const float* W3 = (const float*)d_in[14];
    const float* b3 = (const float*)d_in[15];
    const float* Wc = (const float*)d_in[16];
    const float* bc = (const float*)d_in[17];
    const float* Wl = (const float*)d_in[18];
    const float* bl = (const float*)d_in[19];
    const float* Wa = (const float*)d_in[20];
    const float* ba = (const float*)d_in[21];
    const float* Wb = (const float*)d_in[22];
    const float* bb = (const float*)d_in[23];
    const float* Wo = (const float*)d_in[24];
    const float* bo = (const float*)d_in[25];
    float* out = (float*)d_out;

    char* ws = (char*)d_ws;
    float* x0  = (float*)(ws + O_X0);
    int*   idx = (int*)  (ws + O_IDX);
    float* x1  = (float*)(ws + O_X1);
    float* uv  = (float*)(ws + O_UV);
    u64*   pk  = (u64*)  (ws + O_UV);   // packed knn partials overlay uv (dead until k_uv)
    float* W1f = (float*)(ws + O_WT);
    float* b1f = W1f + 512;
    float* W2f = b1f + 64;
    float* b2f = W2f + 4096;
    float* Wuv = b2f + 64;
    unsigned* out2enc = (unsigned*)(Wuv + 64*256);

    k_fold <<<1, 256, 0, stream>>>(W1,b1,g1,be1,m1,v1, W2,b2,g2,be2,m2,v2, Wc,
                                   W1f,b1f,W2f,b2f,Wuv,out2enc);
    k_x0   <<<NPTS/256, 256, 0, stream>>>(pos, feat, x0);
    k_knn_part <<<BGRAPH*16*SEG, 256, 0, stream>>>(x0, pk);
    k_knn_merge<<<NPTS/256, 256, 0, stream>>>(pk, idx);
    k_conv1<<<NPTS/PTS, 64, 0, stream>>>(x0, idx, W1f, b1f, W2f, b2f, W3, b3, x1);
    k_uv   <<<NPTS/64, 256, 0, stream>>>(x1, Wuv, bc, uv);
    k_x2   <<<NPTS/2, 256, 0, stream>>>(idx, uv);
    dim3 g5(8, 1024);
    k_out1 <<<g5, 256, 0, stream>>>(x1, uv, Wl, bl, out2enc);
    k_head <<<BGRAPH, 256, 0, stream>>>(out2enc, Wa,ba,Wb,bb,Wo,bo, out);
}

// Round 6
// 1673.171 us; speedup vs baseline: 2.4239x; 1.1298x over previous
//
#include <hip/hip_runtime.h>
#include <math.h>

#define BGRAPH 16
#define NPG    4096
#define NPTS   (BGRAPH*NPG)   // 65536
#define KNN    20
#define NC     40
#define EPSBN  1e-5f
#define SEG    4
#define BIGF   3.0e38f

typedef _Float16 half8 __attribute__((ext_vector_type(8)));
typedef _Float16 h2 __attribute__((ext_vector_type(2)));
typedef unsigned long long u64;

// ---------------- ws layout (bytes) ----------------
#define O_X0   0u               // float[NPTS*4]      1 MB
#define O_IDX  1048576u         // int[NPTS*20]       5 MB
#define O_X1   6291456u         // float[NPTS*64]     16 MB
#define O_UV   23068672u        // float[NPTS*256]    64 MB (knn packed partial lists overlay this)
#define O_WT   90177536u        // folded weights + out2enc

// ---------------- helpers ----------------
__device__ __forceinline__ unsigned encf(float v) {
    unsigned u = __float_as_uint(v);
    return (u & 0x80000000u) ? ~u : (u | 0x80000000u);
}
__device__ __forceinline__ float decf(unsigned k) {
    unsigned u = (k & 0x80000000u) ? (k ^ 0x80000000u) : ~k;
    return __uint_as_float(u);
}
// monotone orderable uint from float (handles negatives); strictly monotone in float order
__device__ __forceinline__ unsigned ordf(float f) {
    unsigned u = __float_as_uint(f);
    return u ^ (((unsigned)((int)u >> 31)) | 0x80000000u);
}
// deterministic distance: identical instruction sequence at every use site
__device__ __forceinline__ float distf(float4 xi, float sqi, float4 xj, float sqj) {
    float dot = xi.x * xj.x;
    dot = fmaf(xi.y, xj.y, dot);
    dot = fmaf(xi.z, xj.z, dot);
    dot = fmaf(xi.w, xj.w, dot);
    return fmaf(-2.0f, dot, sqi + sqj);
}
__device__ __forceinline__ float fdot2f(h2 a, h2 b, float c) {
#if __has_builtin(__builtin_amdgcn_fdot2)
    return __builtin_amdgcn_fdot2(a, b, c, false);
#else
    return fmaf((float)a[0], (float)b[0], fmaf((float)a[1], (float)b[1], c));
#endif
}

// 20-slot branchless compare-exchange insert on ORDERABLE U32 (v_min_u32/v_max_u32:
// no float canonicalization, half the u64 register pressure).
// w19 = best (smallest) ... w0 = worst kept (the 20th smallest = tau).
#define TK_DECL unsigned w0=0xFFFFFFFFu,w1=0xFFFFFFFFu,w2=0xFFFFFFFFu,w3=0xFFFFFFFFu,w4=0xFFFFFFFFu, \
    w5=0xFFFFFFFFu,w6=0xFFFFFFFFu,w7=0xFFFFFFFFu,w8=0xFFFFFFFFu,w9=0xFFFFFFFFu, \
    w10=0xFFFFFFFFu,w11=0xFFFFFFFFu,w12=0xFFFFFFFFu,w13=0xFFFFFFFFu,w14=0xFFFFFFFFu, \
    w15=0xFFFFFFFFu,w16=0xFFFFFFFFu,w17=0xFFFFFFFFu,w18=0xFFFFFFFFu,w19=0xFFFFFFFFu;
#define TK_STEP(S) t2 = (cu < S) ? cu : S; cu = (cu < S) ? S : cu; S = t2;
#define TK_INSERT(uv_) { unsigned cu = (uv_), t2; \
    TK_STEP(w19) TK_STEP(w18) TK_STEP(w17) TK_STEP(w16) TK_STEP(w15) \
    TK_STEP(w14) TK_STEP(w13) TK_STEP(w12) TK_STEP(w11) TK_STEP(w10) \
    TK_STEP(w9)  TK_STEP(w8)  TK_STEP(w7)  TK_STEP(w6)  TK_STEP(w5)  \
    TK_STEP(w4)  TK_STEP(w3)  TK_STEP(w2)  TK_STEP(w1)  TK_STEP(w0)  }

// ---------------- K0: fold BN into weights, build Wuv, zero pool accumulators ----------------
__global__ void k_fold(const float* __restrict__ W1, const float* __restrict__ b1,
                       const float* __restrict__ g1, const float* __restrict__ be1,
                       const float* __restrict__ m1, const float* __restrict__ v1,
                       const float* __restrict__ W2, const float* __restrict__ b2,
                       const float* __restrict__ g2, const float* __restrict__ be2,
                       const float* __restrict__ m2, const float* __restrict__ v2,
                       const float* __restrict__ Wc,
                       float* __restrict__ W1f, float* __restrict__ b1f,
                       float* __restrict__ W2f, float* __restrict__ b2f,
                       float* __restrict__ Wuv, unsigned* __restrict__ out2enc)
{
    int t = threadIdx.x;
    for (int i = t; i < 64; i += 256) {
        float s1 = g1[i] * rsqrtf(v1[i] + EPSBN);
        b1f[i] = (b1[i] - m1[i]) * s1 + be1[i];
        float s2 = g2[i] * rsqrtf(v2[i] + EPSBN);
        b2f[i] = (b2[i] - m2[i]) * s2 + be2[i];
    }
    for (int i = t; i < 8*64; i += 256) {
        int c = i & 63;
        W1f[i] = W1[i] * (g1[c] * rsqrtf(v1[c] + EPSBN));
    }
    for (int i = t; i < 64*64; i += 256) {
        int c = i & 63;
        W2f[i] = W2[i] * (g2[c] * rsqrtf(v2[c] + EPSBN));
    }
    for (int i = t; i < 64*256; i += 256) {
        int d = i >> 8, c = i & 255;
        Wuv[i] = (c < 128) ? (Wc[d*128 + c] - Wc[(64+d)*128 + c])
                           : Wc[(64+d)*128 + (c - 128)];
    }
    for (int i = t; i < 16*1024; i += 256) out2enc[i] = 0u;
}

// ---------------- K0b: x0 = [pos | feat] ----------------
__global__ void k_x0(const float* __restrict__ pos, const float* __restrict__ feat,
                     float* __restrict__ x0)
{
    int i = blockIdx.x*256 + threadIdx.x;
    if (i < NPTS) {
        float4 v;
        v.x = pos[i*3+0]; v.y = pos[i*3+1]; v.z = pos[i*3+2]; v.w = feat[i];
        ((float4*)x0)[i] = v;
    }
}

// ---------------- K1a: segmented kNN partials (u32 value-phase + index recovery) ----------
__global__ __launch_bounds__(256, 2) void k_knn_part(const float* __restrict__ x0,
        u64* __restrict__ pk)
{
    __shared__ float4 pts[1024];
    __shared__ float  sqs[1024];
    int x  = blockIdx.x;
    int b  = x >> 6;
    int rb = (x >> 2) & 15;
    int s  = x & 3;
    int t  = threadIdx.x;
    int r  = b*NPG + rb*256 + t;
    float4 xi = ((const float4*)x0)[r];
    float sqi = xi.x*xi.x + xi.y*xi.y + xi.z*xi.z + xi.w*xi.w;
    #pragma unroll
    for (int l = 0; l < 4; ++l) {
        float4 v = ((const float4*)x0)[b*NPG + s*1024 + l*256 + t];
        pts[l*256 + t] = v;
        sqs[l*256 + t] = v.x*v.x + v.y*v.y + v.z*v.z + v.w*v.w;
    }
    __syncthreads();

    TK_DECL
    for (int j = 0; j < 1024; ++j) {
        float d = distf(xi, sqi, pts[j], sqs[j]);
        unsigned u = ordf(d);
        TK_INSERT(u)
    }
    unsigned tauU = w0;   // 20th smallest (orderable u32) in this segment

    int jbase = b*NPG + s*1024;
    u64* pcol = pk + (size_t)s*KNN*NPTS + r;
    unsigned cnt = 0;
    // pass 2a: strictly smaller than tau (provably <= 19 of these)
    for (int j = 0; j < 1024; ++j) {
        float d = distf(xi, sqi, pts[j], sqs[j]);
        unsigned u = ordf(d);
        if (u < tauU && cnt < KNN) {
            pcol[(size_t)cnt*NPTS] = ((u64)u << 32) | (unsigned)(jbase + j);
            cnt++;
        }
    }
    // pass 2b: equal to tau, in increasing index order, fill to 20
    for (int j = 0; j < 1024; ++j) {
        float d = distf(xi, sqi, pts[j], sqs[j]);
        unsigned u = ordf(d);
        if (u == tauU && cnt < KNN) {
            pcol[(size_t)cnt*NPTS] = ((u64)u << 32) | (unsigned)(jbase + j);
            cnt++;
        }
    }
    // defensive fill (unreachable in practice)
    while (cnt < KNN) {
        pcol[(size_t)cnt*NPTS] = ((u64)0xFFFFFFFFu << 32) | (unsigned)r;
        cnt++;
    }
}

// ---------------- K1b: merge 4 partial lists -> final 20 indices (set only) --------
__global__ __launch_bounds__(256, 2) void k_knn_merge(const u64* __restrict__ pk,
        int* __restrict__ idx)
{
    int r = blockIdx.x*256 + threadIdx.x;
    const unsigned* ph = (const unsigned*)pk;   // hi word (ordf value) of slot q at ((q*NPTS + r)*2 + 1)

    TK_DECL
    #pragma unroll 4
    for (int q = 0; q < SEG*KNN; ++q) {
        unsigned u = ph[((size_t)q*NPTS + r)*2 + 1];
        TK_INSERT(u)
    }
    unsigned tauU = w0;   // 20th smallest overall

    unsigned cnt = 0;
    int* o = idx + (size_t)r*KNN;
    for (int q = 0; q < SEG*KNN; ++q) {
        u64 key = pk[(size_t)q*NPTS + r];
        unsigned u = (unsigned)(key >> 32);
        if (u < tauU && cnt < KNN) { o[cnt] = (int)(unsigned)key; cnt++; }
    }
    for (int q = 0; q < SEG*KNN; ++q) {
        u64 key = pk[(size_t)q*NPTS + r];
        unsigned u = (unsigned)(key >> 32);
        if (u == tauU && cnt < KNN) { o[cnt] = (int)(unsigned)key; cnt++; }
    }
    while (cnt < KNN) { o[cnt] = r; cnt++; }
}

// ---------------- K2: EdgeConv1, one wave per block, fp16 LDS staging + v_dot2 ----------------
#define PTS 16
__global__ __launch_bounds__(64) void k_conv1(const float* __restrict__ x0, const int* __restrict__ idx,
        const float* __restrict__ W1f, const float* __restrict__ b1f,
        const float* __restrict__ W2f, const float* __restrict__ b2f,
        const float* __restrict__ W3,  const float* __restrict__ b3,
        float* __restrict__ x1)
{
    __shared__ _Float16 hs0[20*64];
    __shared__ _Float16 hs1[20*64];
    int c = threadIdx.x;
    float w1c[8];
    h2 w2h[32], w3h[32];
    #pragma unroll
    for (int f = 0; f < 8; ++f)  w1c[f] = W1f[f*64 + c];
    #pragma unroll
    for (int m = 0; m < 32; ++m) {
        h2 a; a[0] = (_Float16)W2f[(2*m)*64 + c]; a[1] = (_Float16)W2f[(2*m+1)*64 + c];
        w2h[m] = a;
        h2 b; b[0] = (_Float16)W3[(2*m)*64 + c];  b[1] = (_Float16)W3[(2*m+1)*64 + c];
        w3h[m] = b;
    }
    float b1c = b1f[c], b2c = b2f[c], b3c = b3[c];

    #pragma unroll 1
    for (int pp = 0; pp < PTS; ++pp) {
        int i = blockIdx.x*PTS + pp;
        float4 xi = ((const float4*)x0)[i];
        #pragma unroll 4
        for (int k = 0; k < KNN; ++k) {
            int j = idx[i*KNN + k];
            float4 xj = ((const float4*)x0)[j];
            float h = b1c + xi.x*w1c[0] + xi.y*w1c[1] + xi.z*w1c[2] + xi.w*w1c[3]
                          + (xj.x-xi.x)*w1c[4] + (xj.y-xi.y)*w1c[5]
                          + (xj.z-xi.z)*w1c[6] + (xj.w-xi.w)*w1c[7];
            hs0[k*64 + c] = (_Float16)fmaxf(h, 0.0f);
        }
        __syncthreads();
        // L2: h2v = relu(h1 @ W2f + b2f), 5 parallel chains, v_dot2_f32_f16
        #pragma unroll 1
        for (int kc = 0; kc < 4; ++kc) {
            float acc[5];
            #pragma unroll
            for (int k5 = 0; k5 < 5; ++k5) acc[k5] = b2c;
            #pragma unroll
            for (int q = 0; q < 8; ++q) {
                #pragma unroll
                for (int k5 = 0; k5 < 5; ++k5) {
                    half8 hv = *(const half8*)&hs0[(kc*5 + k5)*64 + q*8];
                    acc[k5] = fdot2f(__builtin_shufflevector(hv, hv, 0, 1), w2h[q*4+0], acc[k5]);
                    acc[k5] = fdot2f(__builtin_shufflevector(hv, hv, 2, 3), w2h[q*4+1], acc[k5]);
                    acc[k5] = fdot2f(__builtin_shufflevector(hv, hv, 4, 5), w2h[q*4+2], acc[k5]);
                    acc[k5] = fdot2f(__builtin_shufflevector(hv, hv, 6, 7), w2h[q*4+3], acc[k5]);
                }
            }
            #pragma unroll
            for (int k5 = 0; k5 < 5; ++k5)
                hs1[(kc*5 + k5)*64 + c] = (_Float16)fmaxf(acc[k5], 0.0f);
        }
        __syncthreads();
        // L3: h3 = h2v @ W3 + b3 (no relu), max over k
        float mx = -3.0e38f;
        #pragma unroll 1
        for (int kc = 0; kc < 4; ++kc) {
            float acc[5];
            #pragma unroll
            for (int k5 = 0; k5 < 5; ++k5) acc[k5] = b3c;
            #pragma unroll
            for (int q = 0; q < 8; ++q) {
                #pragma unroll
                for (int k5 = 0; k5 < 5; ++k5) {
                    half8 hv = *(const half8*)&hs1[(kc*5 + k5)*64 + q*8];
                    acc[k5] = fdot2f(__builtin_shufflevector(hv, hv, 0, 1), w3h[q*4+0], acc[k5]);
                    acc[k5] = fdot2f(__builtin_shufflevector(hv, hv, 2, 3), w3h[q*4+1], acc[k5]);
                    acc[k5] = fdot2f(__builtin_shufflevector(hv, hv, 4, 5), w3h[q*4+2], acc[k5]);
                    acc[k5] = fdot2f(__builtin_shufflevector(hv, hv, 6, 7), w3h[q*4+3], acc[k5]);
                }
            }
            #pragma unroll
            for (int k5 = 0; k5 < 5; ++k5) mx = fmaxf(mx, acc[k5]);
        }
        x1[(size_t)i*64 + c] = mx;
        __syncthreads();
    }
}

// ---------------- K3: uv = x1 @ [Wu | Wv]  (u' gets +bc) ----------------
__global__ __launch_bounds__(256) void k_uv(const float* __restrict__ x1, const float* __restrict__ Wuv,
                                            const float* __restrict__ bc, float* __restrict__ uv)
{
    __shared__ float4 As[64*16];  // 64 rows x 64 cols of x1
    int m0 = blockIdx.x * 64;
    int t  = threadIdx.x;
    #pragma unroll
    for (int l = 0; l < 4; ++l) {
        int lin = l*256 + t;  // 0..1023
        As[lin] = ((const float4*)x1)[(size_t)m0*16 + lin];
    }
    __syncthreads();
    int c = t;  // 0..255
    float acc[64];
    #pragma unroll
    for (int p = 0; p < 64; ++p) acc[p] = 0.f;
    for (int dq = 0; dq < 16; ++dq) {
        float bv0 = Wuv[(dq*4+0)*256 + c];
        float bv1 = Wuv[(dq*4+1)*256 + c];
        float bv2 = Wuv[(dq*4+2)*256 + c];
        float bv3 = Wuv[(dq*4+3)*256 + c];
        #pragma unroll
        for (int p = 0; p < 64; ++p) {
            float4 a = As[p*16 + dq];
            acc[p] += a.x*bv0 + a.y*bv1 + a.z*bv2 + a.w*bv3;
        }
    }
    float badd = (c < 128) ? bc[c] : 0.0f;
    #pragma unroll
    for (int p = 0; p < 64; ++p)
        uv[(size_t)(m0+p)*256 + c] = acc[p] + badd;
}

// ---------------- K4: x2 = u' + max_k v[nbr]  (in-place into u' half of uv) ----------------
__global__ __launch_bounds__(256) void k_x2(const int* __restrict__ idx, float* __restrict__ uv)
{
    int p = blockIdx.x*2 + (threadIdx.x >> 7);
    int c = threadIdx.x & 127;
    float m = -3.0e38f;
    #pragma unroll
    for (int k = 0; k < KNN; ++k) {
        int j = idx[p*KNN + k];
        m = fmaxf(m, uv[(size_t)j*256 + 128 + c]);
    }
    uv[(size_t)p*256 + c] += m;
}

// ---------------- K5: out1 = [x1|x2] @ Wl (+bl), fused per-graph max-pool via atomicMax ----------------
__global__ __launch_bounds__(256) void k_out1(const float* __restrict__ x1, const float* __restrict__ uv,
        const float* __restrict__ Wl, const float* __restrict__ bl, unsigned* __restrict__ out2enc)
{
    __shared__ float As[64][68];
    __shared__ float Bs[64][128];
    int n0 = blockIdx.x * 128;   // 8 col-blocks
    int m0 = blockIdx.y * 64;    // 1024 row-blocks (graph-aligned: 64 | 4096)
    int t  = threadIdx.x;
    int tx = t & 15, ty = t >> 4;
    float acc[4][8];
    #pragma unroll
    for (int i = 0; i < 4; ++i)
        #pragma unroll
        for (int j = 0; j < 8; ++j) acc[i][j] = 0.f;

    for (int kc = 0; kc < 3; ++kc) {
        __syncthreads();
        {
            const float* src = (kc == 0) ? (x1 + (size_t)m0*64) : (uv + (size_t)m0*256 + (kc-1)*64);
            int sstride = (kc == 0) ? 64 : 256;
            #pragma unroll
            for (int l = 0; l < 4; ++l) {
                int lin = l*256 + t;           // 0..1023
                int row = lin >> 4, q = lin & 15;
                float4 v = *(const float4*)(src + (size_t)row*sstride + q*4);
                As[row][q*4+0] = v.x; As[row][q*4+1] = v.y;
                As[row][q*4+2] = v.z; As[row][q*4+3] = v.w;
            }
        }
        #pragma unroll
        for (int l = 0; l < 8; ++l) {
            int lin = l*256 + t;               // 0..2047
            int row = lin >> 5, q = lin & 31;
            float4 v = *(const float4*)(Wl + (size_t)(kc*64 + row)*1024 + n0 + q*4);
            *(float4*)&Bs[row][q*4] = v;
        }
        __syncthreads();
        #pragma unroll 8
        for (int kk = 0; kk < 64; ++kk) {
            float a[4], bvs[8];
            #pragma unroll
            for (int i = 0; i < 4; ++i) a[i] = As[ty*4+i][kk];
            #pragma unroll
            for (int j = 0; j < 8; ++j) bvs[j] = Bs[kk][tx*8+j];
            #pragma unroll
            for (int i = 0; i < 4; ++i)
                #pragma unroll
                for (int j = 0; j < 8; ++j) acc[i][j] += a[i]*bvs[j];
        }
    }
    float cm[8];
    #pragma unroll
    for (int j = 0; j < 8; ++j) {
        float m = acc[0][j];
        #pragma unroll
        for (int i = 1; i < 4; ++i) m = fmaxf(m, acc[i][j]);
        cm[j] = m + bl[n0 + tx*8 + j];
    }
    __syncthreads();
    float* red = &As[0][0];  // reuse: [16][128]
    #pragma unroll
    for (int j = 0; j < 8; ++j) red[ty*128 + tx*8 + j] = cm[j];
    __syncthreads();
    if (ty == 0) {
        int g = m0 >> 12;  // graph id
        #pragma unroll
        for (int j = 0; j < 8; ++j) {
            int cc = tx*8 + j;
            float m = red[cc];
            #pragma unroll
            for (int r2 = 1; r2 < 16; ++r2) m = fmaxf(m, red[r2*128 + cc]);
            atomicMax(&out2enc[g*1024 + n0 + cc], encf(m));
        }
    }
}

// ---------------- K6: per-graph head MLP + log_softmax ----------------
__global__ __launch_bounds__(256) void k_head(const unsigned* __restrict__ out2enc,
        const float* __restrict__ Wa, const float* __restrict__ ba,
        const float* __restrict__ Wb, const float* __restrict__ bb,
        const float* __restrict__ Wo, const float* __restrict__ bo,
        float* __restrict__ out)
{
    __shared__ float s1[1024];
    __shared__ float s2[512];
    __shared__ float s3[256];
    __shared__ float sl[NC];
    int g = blockIdx.x, t = threadIdx.x;
    for (int i = t; i < 1024; i += 256) s1[i] = decf(out2enc[g*1024 + i]);
    __syncthreads();
    for (int cc = t; cc < 512; cc += 256) {
        float a = ba[cc];
        #pragma unroll 8
        for (int d = 0; d < 1024; ++d) a += s1[d] * Wa[(size_t)d*512 + cc];
        s2[cc] = fmaxf(a, 0.f);
    }
    __syncthreads();
    if (t < 256) {
        float a = bb[t];
        #pragma unroll 8
        for (int d = 0; d < 512; ++d) a += s2[d] * Wb[(size_t)d*256 + t];
        s3[t] = fmaxf(a, 0.f);
    }
    __syncthreads();
    if (t < NC) {
        float a = bo[t];
        #pragma unroll 8
        for (int d = 0; d < 256; ++d) a += s3[d] * Wo[d*NC + t];
        sl[t] = a;
    }
    __syncthreads();
    if (t < 64) {
        float v = (t < NC) ? sl[t] : -3.0e38f;
        float m = v;
        #pragma unroll
        for (int o2 = 32; o2 >= 1; o2 >>= 1) m = fmaxf(m, __shfl_xor(m, o2));
        float e = (t < NC) ? expf(sl[t] - m) : 0.f;
        float s = e;
        #pragma unroll
        for (int o2 = 32; o2 >= 1; o2 >>= 1) s += __shfl_xor(s, o2);
        float ls = logf(s) + m;
        if (t < NC) out[g*NC + t] = sl[t] - ls;
    }
}

// ---------------- launch ----------------
extern "C" void kernel_launch(void* const* d_in, const int* in_sizes, int n_in,
                              void* d_out, int out_size, void* d_ws, size_t ws_size,
                              hipStream_t stream)
{
    const float* pos  = (const float*)d_in[0];
    const float* feat = (const float*)d_in[1];
    const float* W1 = (const float*)d_in[2];
    const float* b1 = (const float*)d_in[3];
    const float* g1 = (const float*)d_in[4];
    const float* be1= (const float*)d_in[5];
    const float* m1 = (const float*)d_in[6];
    const float* v1 = (const float*)d_in[7];
    const float* W2 = (const float*)d_in[8];
    const float* b2 = (const float*)d_in[9];
    const float* g2 = (const float*)d_in[10];
    const float* be2= (const float*)d_in[11];
    const float* m2 = (const float*)d_in[12];
    const float* v2 = (const float*)d_in[13];
    const float* W3 = (const float*)d_in[14];
    const float* b3 = (const float*)d_in[15];
    const float* Wc = (const float*)d_in[16];
    const float* bc = (const float*)d_in[17];
    const float* Wl = (const float*)d_in[18];
    const float* bl = (const float*)d_in[19];
    const float* Wa = (const float*)d_in[20];
    const float* ba = (const float*)d_in[21];
    const float* Wb = (const float*)d_in[22];
    const float* bb = (const float*)d_in[23];
    const float* Wo = (const float*)d_in[24];
    const float* bo = (const float*)d_in[25];
    float* out = (float*)d_out;

    char* ws = (char*)d_ws;
    float* x0  = (float*)(ws + O_X0);
    int*   idx = (int*)  (ws + O_IDX);
    float* x1  = (float*)(ws + O_X1);
    float* uv  = (float*)(ws + O_UV);
    u64*   pk  = (u64*)  (ws + O_UV);   // packed knn partials overlay uv (dead until k_uv)
    float* W1f = (float*)(ws + O_WT);
    float* b1f = W1f + 512;
    float* W2f = b1f + 64;
    float* b2f = W2f + 4096;
    float* Wuv = b2f + 64;
    unsigned* out2enc = (unsigned*)(Wuv + 64*256);

    k_fold <<<1, 256, 0, stream>>>(W1,b1,g1,be1,m1,v1, W2,b2,g2,be2,m2,v2, Wc,
                                   W1f,b1f,W2f,b2f,Wuv,out2enc);
    k_x0   <<<NPTS/256, 256, 0, stream>>>(pos, feat, x0);
    k_knn_part <<<BGRAPH*16*SEG, 256, 0, stream>>>(x0, pk);
    k_knn_merge<<<NPTS/256, 256, 0, stream>>>(pk, idx);
    k_conv1<<<NPTS/PTS, 64, 0, stream>>>(x0, idx, W1f, b1f, W2f, b2f, W3, b3, x1);
    k_uv   <<<NPTS/64, 256, 0, stream>>>(x1, Wuv, bc, uv);
    k_x2   <<<NPTS/2, 256, 0, stream>>>(idx, uv);
    dim3 g5(8, 1024);
    k_out1 <<<g5, 256, 0, stream>>>(x1, uv, Wl, bl, out2enc);
    k_head <<<BGRAPH, 256, 0, stream>>>(out2enc, Wa,ba,Wb,bb,Wo,bo, out);
}

// Round 7
// 1579.342 us; speedup vs baseline: 2.5679x; 1.0594x over previous
//
#include <hip/hip_runtime.h>
#include <math.h>

#define BGRAPH 16
#define NPG    4096
#define NPTS   (BGRAPH*NPG)   // 65536
#define KNN    20
#define NC     40
#define EPSBN  1e-5f
#define SEG    4

typedef _Float16 half8 __attribute__((ext_vector_type(8)));
typedef _Float16 h4 __attribute__((ext_vector_type(4)));
typedef _Float16 h2 __attribute__((ext_vector_type(2)));
typedef unsigned short ushort8 __attribute__((ext_vector_type(8)));
typedef float f32x4 __attribute__((ext_vector_type(4)));
typedef unsigned long long u64;

// ---------------- ws layout (bytes) ----------------
#define O_X0   0u               // float[NPTS*4]      1 MB
#define O_IDX  1048576u         // int[NPTS*20]       5 MB
#define O_X1   6291456u         // float[NPTS*64]     16 MB
#define O_UV   23068672u        // float[NPTS*256]    64 MB (knn packed partial lists overlay this)
#define O_WT   90177536u        // folded weights + out2enc + Wlh

// ---------------- helpers ----------------
__device__ __forceinline__ unsigned encf(float v) {
    unsigned u = __float_as_uint(v);
    return (u & 0x80000000u) ? ~u : (u | 0x80000000u);
}
__device__ __forceinline__ float decf(unsigned k) {
    unsigned u = (k & 0x80000000u) ? (k ^ 0x80000000u) : ~k;
    return __uint_as_float(u);
}
__device__ __forceinline__ unsigned ordf(float f) {
    unsigned u = __float_as_uint(f);
    return u ^ (((unsigned)((int)u >> 31)) | 0x80000000u);
}
// deterministic distance: identical instruction sequence at every use site
__device__ __forceinline__ float distf(float4 xi, float sqi, float4 xj, float sqj) {
    float dot = xi.x * xj.x;
    dot = fmaf(xi.y, xj.y, dot);
    dot = fmaf(xi.z, xj.z, dot);
    dot = fmaf(xi.w, xj.w, dot);
    return fmaf(-2.0f, dot, sqi + sqj);
}
__device__ __forceinline__ float fdot2f(h2 a, h2 b, float c) {
#if __has_builtin(__builtin_amdgcn_fdot2)
    return __builtin_amdgcn_fdot2(a, b, c, false);
#else
    return fmaf((float)a[0], (float)b[0], fmaf((float)a[1], (float)b[1], c));
#endif
}

// 20-slot global chain: w19 best .. w0 = 20th smallest (tau)
#define TK_DECL unsigned w0=0xFFFFFFFFu,w1=0xFFFFFFFFu,w2=0xFFFFFFFFu,w3=0xFFFFFFFFu,w4=0xFFFFFFFFu, \
    w5=0xFFFFFFFFu,w6=0xFFFFFFFFu,w7=0xFFFFFFFFu,w8=0xFFFFFFFFu,w9=0xFFFFFFFFu, \
    w10=0xFFFFFFFFu,w11=0xFFFFFFFFu,w12=0xFFFFFFFFu,w13=0xFFFFFFFFu,w14=0xFFFFFFFFu, \
    w15=0xFFFFFFFFu,w16=0xFFFFFFFFu,w17=0xFFFFFFFFu,w18=0xFFFFFFFFu,w19=0xFFFFFFFFu;
#define TK_STEP(S) t2 = (cu < S) ? cu : S; cu = (cu < S) ? S : cu; S = t2;
#define TK_INSERT(uv_) { unsigned cu = (uv_), t2; \
    TK_STEP(w19) TK_STEP(w18) TK_STEP(w17) TK_STEP(w16) TK_STEP(w15) \
    TK_STEP(w14) TK_STEP(w13) TK_STEP(w12) TK_STEP(w11) TK_STEP(w10) \
    TK_STEP(w9)  TK_STEP(w8)  TK_STEP(w7)  TK_STEP(w6)  TK_STEP(w5)  \
    TK_STEP(w4)  TK_STEP(w3)  TK_STEP(w2)  TK_STEP(w1)  TK_STEP(w0)  }

// 10-slot per-subsegment chain
#define TK10_INS(uv_) { unsigned cu = (uv_), t2; \
    TK_STEP(m9) TK_STEP(m8) TK_STEP(m7) TK_STEP(m6) TK_STEP(m5) \
    TK_STEP(m4) TK_STEP(m3) TK_STEP(m2) TK_STEP(m1) TK_STEP(m0) }

// scan subsegment SS (128 candidates) with top-10 chain, save worst-kept, merge into 20-chain
#define SEG_SCAN(SS, SAVE) { \
    unsigned m0=0xFFFFFFFFu,m1=0xFFFFFFFFu,m2=0xFFFFFFFFu,m3=0xFFFFFFFFu,m4=0xFFFFFFFFu, \
             m5=0xFFFFFFFFu,m6=0xFFFFFFFFu,m7=0xFFFFFFFFu,m8=0xFFFFFFFFu,m9=0xFFFFFFFFu; \
    _Pragma("unroll 1") \
    for (int j = (SS)*128; j < (SS)*128 + 128; ++j) { \
        float d = distf(xi, sqi, pts[j], sqs[j]); \
        unsigned u = ordf(d); \
        TK10_INS(u) \
    } \
    SAVE = m0; \
    TK_INSERT(m9) TK_INSERT(m8) TK_INSERT(m7) TK_INSERT(m6) TK_INSERT(m5) \
    TK_INSERT(m4) TK_INSERT(m3) TK_INSERT(m2) TK_INSERT(m1) TK_INSERT(m0) }

// ---------------- K0: fold BN into weights, build Wuv, zero pool accumulators ----------------
__global__ void k_fold(const float* __restrict__ W1, const float* __restrict__ b1,
                       const float* __restrict__ g1, const float* __restrict__ be1,
                       const float* __restrict__ m1, const float* __restrict__ v1,
                       const float* __restrict__ W2, const float* __restrict__ b2,
                       const float* __restrict__ g2, const float* __restrict__ be2,
                       const float* __restrict__ m2, const float* __restrict__ v2,
                       const float* __restrict__ Wc,
                       float* __restrict__ W1f, float* __restrict__ b1f,
                       float* __restrict__ W2f, float* __restrict__ b2f,
                       float* __restrict__ Wuv, unsigned* __restrict__ out2enc)
{
    int t = threadIdx.x;
    for (int i = t; i < 64; i += 256) {
        float s1 = g1[i] * rsqrtf(v1[i] + EPSBN);
        b1f[i] = (b1[i] - m1[i]) * s1 + be1[i];
        float s2 = g2[i] * rsqrtf(v2[i] + EPSBN);
        b2f[i] = (b2[i] - m2[i]) * s2 + be2[i];
    }
    for (int i = t; i < 8*64; i += 256) {
        int c = i & 63;
        W1f[i] = W1[i] * (g1[c] * rsqrtf(v1[c] + EPSBN));
    }
    for (int i = t; i < 64*64; i += 256) {
        int c = i & 63;
        W2f[i] = W2[i] * (g2[c] * rsqrtf(v2[c] + EPSBN));
    }
    for (int i = t; i < 64*256; i += 256) {
        int d = i >> 8, c = i & 255;
        Wuv[i] = (c < 128) ? (Wc[d*128 + c] - Wc[(64+d)*128 + c])
                           : Wc[(64+d)*128 + (c - 128)];
    }
    for (int i = t; i < 16*1024; i += 256) out2enc[i] = 0u;
}

// ---------------- K0b: x0 = [pos | feat] ----------------
__global__ void k_x0(const float* __restrict__ pos, const float* __restrict__ feat,
                     float* __restrict__ x0)
{
    int i = blockIdx.x*256 + threadIdx.x;
    if (i < NPTS) {
        float4 v;
        v.x = pos[i*3+0]; v.y = pos[i*3+1]; v.z = pos[i*3+2]; v.w = feat[i];
        ((float4*)x0)[i] = v;
    }
}

// ---------------- K0c: Wlh[j][k] = fp16(Wl[k][j])  (transpose, 32x32 LDS tiles) --------
__global__ __launch_bounds__(256) void k_wlh(const float* __restrict__ Wl, _Float16* __restrict__ Wlh)
{
    __shared__ float tile[32][33];
    int jb = blockIdx.x * 32, kb = blockIdx.y * 32;
    int tx = threadIdx.x & 31, ty = threadIdx.x >> 5;  // 8 rows per pass
    #pragma unroll
    for (int r = 0; r < 32; r += 8)
        tile[ty + r][tx] = Wl[(size_t)(kb + ty + r)*1024 + jb + tx];
    __syncthreads();
    #pragma unroll
    for (int r = 0; r < 32; r += 8)
        Wlh[(size_t)(jb + ty + r)*192 + kb + tx] = (_Float16)tile[tx][ty + r];
}

// ---------------- K1a: segmented kNN partials (8x top-10 + exact fallback) ----------
__global__ __launch_bounds__(256, 2) void k_knn_part(const float* __restrict__ x0,
        u64* __restrict__ pk)
{
    __shared__ float4 pts[1024];
    __shared__ float  sqs[1024];
    int x  = blockIdx.x;
    int b  = x >> 6;
    int rb = (x >> 2) & 15;
    int s  = x & 3;
    int t  = threadIdx.x;
    int r  = b*NPG + rb*256 + t;
    float4 xi = ((const float4*)x0)[r];
    float sqi = xi.x*xi.x + xi.y*xi.y + xi.z*xi.z + xi.w*xi.w;
    #pragma unroll
    for (int l = 0; l < 4; ++l) {
        float4 v = ((const float4*)x0)[b*NPG + s*1024 + l*256 + t];
        pts[l*256 + t] = v;
        sqs[l*256 + t] = v.x*v.x + v.y*v.y + v.z*v.z + v.w*v.w;
    }
    __syncthreads();

    TK_DECL
    unsigned s0w, s1w, s2w, s3w, s4w, s5w, s6w, s7w;
    SEG_SCAN(0, s0w) SEG_SCAN(1, s1w) SEG_SCAN(2, s2w) SEG_SCAN(3, s3w)
    SEG_SCAN(4, s4w) SEG_SCAN(5, s5w) SEG_SCAN(6, s6w) SEG_SCAN(7, s7w)
    unsigned tauU = w0;   // 20th smallest of the merged 8x10 lists
    // a subsegment is uncertain if ALL 10 kept values made the global top-20
    bool bad = (s0w <= tauU) || (s1w <= tauU) || (s2w <= tauU) || (s3w <= tauU) ||
               (s4w <= tauU) || (s5w <= tauU) || (s6w <= tauU) || (s7w <= tauU);
    if (bad) {   // rare (<0.1% of lanes): exact full rescan with fresh 20-chain
        w0=w1=w2=w3=w4=w5=w6=w7=w8=w9=0xFFFFFFFFu;
        w10=w11=w12=w13=w14=w15=w16=w17=w18=w19=0xFFFFFFFFu;
        #pragma unroll 1
        for (int j = 0; j < 1024; ++j) {
            float d = distf(xi, sqi, pts[j], sqs[j]);
            unsigned u = ordf(d);
            TK_INSERT(u)
        }
        tauU = w0;
    }

    int jbase = b*NPG + s*1024;
    u64* pcol = pk + (size_t)s*KNN*NPTS + r;
    unsigned cnt = 0;
    // pass 2a: strictly smaller than tau (provably <= 19 of these)
    #pragma unroll 1
    for (int j = 0; j < 1024; ++j) {
        float d = distf(xi, sqi, pts[j], sqs[j]);
        unsigned u = ordf(d);
        if (u < tauU && cnt < KNN) {
            pcol[(size_t)cnt*NPTS] = ((u64)u << 32) | (unsigned)(jbase + j);
            cnt++;
        }
    }
    // pass 2b: equal to tau, in increasing index order, fill to 20
    #pragma unroll 1
    for (int j = 0; j < 1024; ++j) {
        float d = distf(xi, sqi, pts[j], sqs[j]);
        unsigned u = ordf(d);
        if (u == tauU && cnt < KNN) {
            pcol[(size_t)cnt*NPTS] = ((u64)u << 32) | (unsigned)(jbase + j);
            cnt++;
        }
    }
    // defensive fill (unreachable in practice)
    while (cnt < KNN) {
        pcol[(size_t)cnt*NPTS] = ((u64)0xFFFFFFFFu << 32) | (unsigned)r;
        cnt++;
    }
}

// ---------------- K1b: merge 4 partial lists -> final 20 indices (set only) --------
__global__ __launch_bounds__(256, 2) void k_knn_merge(const u64* __restrict__ pk,
        int* __restrict__ idx)
{
    int r = blockIdx.x*256 + threadIdx.x;
    const unsigned* ph = (const unsigned*)pk;   // hi word (ordf value) of slot q

    TK_DECL
    #pragma unroll 4
    for (int q = 0; q < SEG*KNN; ++q) {
        unsigned u = ph[((size_t)q*NPTS + r)*2 + 1];
        TK_INSERT(u)
    }
    unsigned tauU = w0;

    unsigned cnt = 0;
    int* o = idx + (size_t)r*KNN;
    for (int q = 0; q < SEG*KNN; ++q) {
        u64 key = pk[(size_t)q*NPTS + r];
        unsigned u = (unsigned)(key >> 32);
        if (u < tauU && cnt < KNN) { o[cnt] = (int)(unsigned)key; cnt++; }
    }
    for (int q = 0; q < SEG*KNN; ++q) {
        u64 key = pk[(size_t)q*NPTS + r];
        unsigned u = (unsigned)(key >> 32);
        if (u == tauU && cnt < KNN) { o[cnt] = (int)(unsigned)key; cnt++; }
    }
    while (cnt < KNN) { o[cnt] = r; cnt++; }
}

// ---------------- K2: EdgeConv1, one wave per block, fp16 LDS staging + v_dot2 ----------------
#define PTS 16
__global__ __launch_bounds__(64) void k_conv1(const float* __restrict__ x0, const int* __restrict__ idx,
        const float* __restrict__ W1f, const float* __restrict__ b1f,
        const float* __restrict__ W2f, const float* __restrict__ b2f,
        const float* __restrict__ W3,  const float* __restrict__ b3,
        float* __restrict__ x1)
{
    __shared__ _Float16 hs0[20*64];
    __shared__ _Float16 hs1[20*64];
    int c = threadIdx.x;
    float w1c[8];
    h2 w2h[32], w3h[32];
    #pragma unroll
    for (int f = 0; f < 8; ++f)  w1c[f] = W1f[f*64 + c];
    #pragma unroll
    for (int m = 0; m < 32; ++m) {
        h2 a; a[0] = (_Float16)W2f[(2*m)*64 + c]; a[1] = (_Float16)W2f[(2*m+1)*64 + c];
        w2h[m] = a;
        h2 b; b[0] = (_Float16)W3[(2*m)*64 + c];  b[1] = (_Float16)W3[(2*m+1)*64 + c];
        w3h[m] = b;
    }
    float b1c = b1f[c], b2c = b2f[c], b3c = b3[c];

    #pragma unroll 1
    for (int pp = 0; pp < PTS; ++pp) {
        int i = blockIdx.x*PTS + pp;
        float4 xi = ((const float4*)x0)[i];
        #pragma unroll 4
        for (int k = 0; k < KNN; ++k) {
            int j = idx[i*KNN + k];
            float4 xj = ((const float4*)x0)[j];
            float h = b1c + xi.x*w1c[0] + xi.y*w1c[1] + xi.z*w1c[2] + xi.w*w1c[3]
                          + (xj.x-xi.x)*w1c[4] + (xj.y-xi.y)*w1c[5]
                          + (xj.z-xi.z)*w1c[6] + (xj.w-xi.w)*w1c[7];
            hs0[k*64 + c] = (_Float16)fmaxf(h, 0.0f);
        }
        __syncthreads();
        #pragma unroll 1
        for (int kc = 0; kc < 4; ++kc) {
            float acc[5];
            #pragma unroll
            for (int k5 = 0; k5 < 5; ++k5) acc[k5] = b2c;
            #pragma unroll
            for (int q = 0; q < 8; ++q) {
                #pragma unroll
                for (int k5 = 0; k5 < 5; ++k5) {
                    half8 hv = *(const half8*)&hs0[(kc*5 + k5)*64 + q*8];
                    acc[k5] = fdot2f(__builtin_shufflevector(hv, hv, 0, 1), w2h[q*4+0], acc[k5]);
                    acc[k5] = fdot2f(__builtin_shufflevector(hv, hv, 2, 3), w2h[q*4+1], acc[k5]);
                    acc[k5] = fdot2f(__builtin_shufflevector(hv, hv, 4, 5), w2h[q*4+2], acc[k5]);
                    acc[k5] = fdot2f(__builtin_shufflevector(hv, hv, 6, 7), w2h[q*4+3], acc[k5]);
                }
            }
            #pragma unroll
            for (int k5 = 0; k5 < 5; ++k5)
                hs1[(kc*5 + k5)*64 + c] = (_Float16)fmaxf(acc[k5], 0.0f);
        }
        __syncthreads();
        float mx = -3.0e38f;
        #pragma unroll 1
        for (int kc = 0; kc < 4; ++kc) {
            float acc[5];
            #pragma unroll
            for (int k5 = 0; k5 < 5; ++k5) acc[k5] = b3c;
            #pragma unroll
            for (int q = 0; q < 8; ++q) {
                #pragma unroll
                for (int k5 = 0; k5 < 5; ++k5) {
                    half8 hv = *(const half8*)&hs1[(kc*5 + k5)*64 + q*8];
                    acc[k5] = fdot2f(__builtin_shufflevector(hv, hv, 0, 1), w3h[q*4+0], acc[k5]);
                    acc[k5] = fdot2f(__builtin_shufflevector(hv, hv, 2, 3), w3h[q*4+1], acc[k5]);
                    acc[k5] = fdot2f(__builtin_shufflevector(hv, hv, 4, 5), w3h[q*4+2], acc[k5]);
                    acc[k5] = fdot2f(__builtin_shufflevector(hv, hv, 6, 7), w3h[q*4+3], acc[k5]);
                }
            }
            #pragma unroll
            for (int k5 = 0; k5 < 5; ++k5) mx = fmaxf(mx, acc[k5]);
        }
        x1[(size_t)i*64 + c] = mx;
        __syncthreads();
    }
}

// ---------------- K3: uv = x1 @ [Wu | Wv]  (u' gets +bc) ----------------
__global__ __launch_bounds__(256) void k_uv(const float* __restrict__ x1, const float* __restrict__ Wuv,
                                            const float* __restrict__ bc, float* __restrict__ uv)
{
    __shared__ float4 As[64*16];  // 64 rows x 64 cols of x1
    int m0 = blockIdx.x * 64;
    int t  = threadIdx.x;
    #pragma unroll
    for (int l = 0; l < 4; ++l) {
        int lin = l*256 + t;  // 0..1023
        As[lin] = ((const float4*)x1)[(size_t)m0*16 + lin];
    }
    __syncthreads();
    int c = t;  // 0..255
    float acc[64];
    #pragma unroll
    for (int p = 0; p < 64; ++p) acc[p] = 0.f;
    for (int dq = 0; dq < 16; ++dq) {
        float bv0 = Wuv[(dq*4+0)*256 + c];
        float bv1 = Wuv[(dq*4+1)*256 + c];
        float bv2 = Wuv[(dq*4+2)*256 + c];
        float bv3 = Wuv[(dq*4+3)*256 + c];
        #pragma unroll
        for (int p = 0; p < 64; ++p) {
            float4 a = As[p*16 + dq];
            acc[p] += a.x*bv0 + a.y*bv1 + a.z*bv2 + a.w*bv3;
        }
    }
    float badd = (c < 128) ? bc[c] : 0.0f;
    #pragma unroll
    for (int p = 0; p < 64; ++p)
        uv[(size_t)(m0+p)*256 + c] = acc[p] + badd;
}

// ---------------- K4: x2 = u' + max_k v[nbr]  (in-place into u' half of uv) ----------------
__global__ __launch_bounds__(256) void k_x2(const int* __restrict__ idx, float* __restrict__ uv)
{
    int p = blockIdx.x*2 + (threadIdx.x >> 7);
    int c = threadIdx.x & 127;
    float m = -3.0e38f;
    #pragma unroll
    for (int k = 0; k < KNN; ++k) {
        int j = idx[p*KNN + k];
        m = fmaxf(m, uv[(size_t)j*256 + 128 + c]);
    }
    uv[(size_t)p*256 + c] += m;
}

// ---------------- K5: out1 = [x1|x2] @ Wl (+bl) via fp16 MFMA, fused max-pool ------------
// grid (8 N-blocks, 1024 M-blocks), 256 threads (4 waves). Tile 64(M) x 128(N), K=192.
__global__ __launch_bounds__(256) void k_out1(const float* __restrict__ x1, const float* __restrict__ uv,
        const _Float16* __restrict__ Wlh, const float* __restrict__ bl, unsigned* __restrict__ out2enc)
{
    __shared__ _Float16 Asd[64][208];   // 416B row stride -> conflict-free b128 frags
    __shared__ _Float16 Bsd[128][208];
    int n0 = blockIdx.x * 128;
    int m0 = blockIdx.y * 64;
    int t  = threadIdx.x;

    // stage A: row = t>>2, cols [sub*48, sub*48+48): x1 (0..63) | x2=uv[...][0..127] (64..191)
    {
        int row = t >> 2, sub = t & 3;
        const float* xr = x1 + (size_t)(m0 + row)*64;
        const float* ur = uv + (size_t)(m0 + row)*256;
        #pragma unroll
        for (int cc = 0; cc < 12; ++cc) {
            int col = sub*48 + cc*4;
            float4 v = (col < 64) ? *(const float4*)(xr + col)
                                  : *(const float4*)(ur + (col - 64));
            h4 hv;
            hv[0] = (_Float16)v.x; hv[1] = (_Float16)v.y;
            hv[2] = (_Float16)v.z; hv[3] = (_Float16)v.w;
            *(h4*)&Asd[row][col] = hv;
        }
    }
    // stage B: Bsd[j][k] = Wlh[n0+j][k] (vector copies)
    {
        int j = t >> 1, hf = t & 1;
        const ushort8* src = (const ushort8*)(Wlh + (size_t)(n0 + j)*192 + hf*96);
        #pragma unroll
        for (int ch = 0; ch < 12; ++ch)
            *(ushort8*)&Bsd[j][hf*96 + ch*8] = src[ch];
    }
    __syncthreads();

    int w  = t >> 6, l = t & 63;
    int lr = l & 15, lg = l >> 4;
    f32x4 acc[8];
    #pragma unroll
    for (int f = 0; f < 8; ++f) acc[f] = (f32x4){0.f, 0.f, 0.f, 0.f};
    #pragma unroll 1
    for (int ks = 0; ks < 6; ++ks) {
        half8 a = *(const half8*)&Asd[w*16 + lr][ks*32 + lg*8];
        #pragma unroll
        for (int f = 0; f < 8; ++f) {
            half8 b = *(const half8*)&Bsd[f*16 + lr][ks*32 + lg*8];
            acc[f] = __builtin_amdgcn_mfma_f32_16x16x32_f16(a, b, acc[f], 0, 0, 0);
        }
    }
    // epilogue: max over the block's 64 rows per column, +bias, atomicMax
    float cmax[8];
    #pragma unroll
    for (int f = 0; f < 8; ++f) {
        float m = fmaxf(fmaxf(acc[f][0], acc[f][1]), fmaxf(acc[f][2], acc[f][3]));
        m = fmaxf(m, __shfl_xor(m, 16));
        m = fmaxf(m, __shfl_xor(m, 32));
        cmax[f] = m;   // lanes with equal lr now hold the wave's 16-row col-max
    }
    __syncthreads();                     // done reading Asd; reuse as reduction scratch
    float* red = (float*)&Asd[0][0];     // [4][128]
    if (l < 16) {
        #pragma unroll
        for (int f = 0; f < 8; ++f) red[w*128 + f*16 + l] = cmax[f];
    }
    __syncthreads();
    if (t < 128) {
        float m = fmaxf(fmaxf(red[t], red[128 + t]), fmaxf(red[256 + t], red[384 + t]));
        m += bl[n0 + t];
        int g = m0 >> 12;
        atomicMax(&out2enc[g*1024 + n0 + t], encf(m));
    }
}

// ---------------- K6: per-graph head MLP + log_softmax ----------------
__global__ __launch_bounds__(256) void k_head(const unsigned* __restrict__ out2enc,
        const float* __restrict__ Wa, const float* __restrict__ ba,
        const float* __restrict__ Wb, const float* __restrict__ bb,
        const float* __restrict__ Wo, const float* __restrict__ bo,
        float* __restrict__ out)
{
    __shared__ float s1[1024];
    __shared__ float s2[512];
    __shared__ float s3[256];
    __shared__ float sl[NC];
    int g = blockIdx.x, t = threadIdx.x;
    for (int i = t; i < 1024; i += 256) s1[i] = decf(out2enc[g*1024 + i]);
    __syncthreads();
    for (int cc = t; cc < 512; cc += 256) {
        float a = ba[cc];
        #pragma unroll 8
        for (int d = 0; d < 1024; ++d) a += s1[d] * Wa[(size_t)d*512 + cc];
        s2[cc] = fmaxf(a, 0.f);
    }
    __syncthreads();
    if (t < 256) {
        float a = bb[t];
        #pragma unroll 8
        for (int d = 0; d < 512; ++d) a += s2[d] * Wb[(size_t)d*256 + t];
        s3[t] = fmaxf(a, 0.f);
    }
    __syncthreads();
    if (t < NC) {
        float a = bo[t];
        #pragma unroll 8
        for (int d = 0; d < 256; ++d) a += s3[d] * Wo[d*NC + t];
        sl[t] = a;
    }
    __syncthreads();
    if (t < 64) {
        float v = (t < NC) ? sl[t] : -3.0e38f;
        float m = v;
        #pragma unroll
        for (int o2 = 32; o2 >= 1; o2 >>= 1) m = fmaxf(m, __shfl_xor(m, o2));
        float e = (t < NC) ? expf(sl[t] - m) : 0.f;
        float s = e;
        #pragma unroll
        for (int o2 = 32; o2 >= 1; o2 >>= 1) s += __shfl_xor(s, o2);
        float ls = logf(s) + m;
        if (t < NC) out[g*NC + t] = sl[t] - ls;
    }
}

// ---------------- launch ----------------
extern "C" void kernel_launch(void* const* d_in, const int* in_sizes, int n_in,
                              void* d_out, int out_size, void* d_ws, size_t ws_size,
                              hipStream_t stream)
{
    const float* pos  = (const float*)d_in[0];
    const float* feat = (const float*)d_in[1];
    const float* W1 = (const float*)d_in[2];
    const float* b1 = (const float*)d_in[3];
    const float* g1 = (const float*)d_in[4];
    const float* be1= (const float*)d_in[5];
    const float* m1 = (const float*)d_in[6];
    const float* v1 = (const float*)d_in[7];
    const float* W2 = (const float*)d_in[8];
    const float* b2 = (const float*)d_in[9];
    const float* g2 = (const float*)d_in[10];
    const float* be2= (const float*)d_in[11];
    const float* m2 = (const float*)d_in[12];
    const float* v2 = (const float*)d_in[13];
    const float* W3 = (const float*)d_in[14];
    const float* b3 = (const float*)d_in[15];
    const float* Wc = (const float*)d_in[16];
    const float* bc = (const float*)d_in[17];
    const float* Wl = (const float*)d_in[18];
    const float* bl = (const float*)d_in[19];
    const float* Wa = (const float*)d_in[20];
    const float* ba = (const float*)d_in[21];
    const float* Wb = (const float*)d_in[22];
    const float* bb = (const float*)d_in[23];
    const float* Wo = (const float*)d_in[24];
    const float* bo = (const float*)d_in[25];
    float* out = (float*)d_out;

    char* ws = (char*)d_ws;
    float* x0  = (float*)(ws + O_X0);
    int*   idx = (int*)  (ws + O_IDX);
    float* x1  = (float*)(ws + O_X1);
    float* uv  = (float*)(ws + O_UV);
    u64*   pk  = (u64*)  (ws + O_UV);   // packed knn partials overlay uv (dead until k_uv)
    float* W1f = (float*)(ws + O_WT);
    float* b1f = W1f + 512;
    float* W2f = b1f + 64;
    float* b2f = W2f + 4096;
    float* Wuv = b2f + 64;
    unsigned* out2enc = (unsigned*)(Wuv + 64*256);
    _Float16* Wlh = (_Float16*)(ws + O_WT + 262144);   // 1024x192 fp16 = 384 KB

    k_fold <<<1, 256, 0, stream>>>(W1,b1,g1,be1,m1,v1, W2,b2,g2,be2,m2,v2, Wc,
                                   W1f,b1f,W2f,b2f,Wuv,out2enc);
    k_x0   <<<NPTS/256, 256, 0, stream>>>(pos, feat, x0);
    dim3 gw(32, 6);
    k_wlh  <<<gw, 256, 0, stream>>>(Wl, Wlh);
    k_knn_part <<<BGRAPH*16*SEG, 256, 0, stream>>>(x0, pk);
    k_knn_merge<<<NPTS/256, 256, 0, stream>>>(pk, idx);
    k_conv1<<<NPTS/PTS, 64, 0, stream>>>(x0, idx, W1f, b1f, W2f, b2f, W3, b3, x1);
    k_uv   <<<NPTS/64, 256, 0, stream>>>(x1, Wuv, bc, uv);
    k_x2   <<<NPTS/2, 256, 0, stream>>>(idx, uv);
    dim3 g5(8, 1024);
    k_out1 <<<g5, 256, 0, stream>>>(x1, uv, Wlh, bl, out2enc);
    k_head <<<BGRAPH, 256, 0, stream>>>(out2enc, Wa,ba,Wb,bb,Wo,bo, out);
}

// Round 8
// 1318.293 us; speedup vs baseline: 3.0763x; 1.1980x over previous
//
#include <hip/hip_runtime.h>
#include <math.h>

#define BGRAPH 16
#define NPG    4096
#define NPTS   (BGRAPH*NPG)   // 65536
#define KNN    20
#define NC     40
#define EPSBN  1e-5f
#define SEG    4

typedef _Float16 half8 __attribute__((ext_vector_type(8)));
typedef _Float16 h4 __attribute__((ext_vector_type(4)));
typedef _Float16 h2 __attribute__((ext_vector_type(2)));
typedef unsigned short ushort8 __attribute__((ext_vector_type(8)));
typedef float f32x4 __attribute__((ext_vector_type(4)));
typedef unsigned long long u64;

// ---------------- ws layout (bytes) ----------------
#define O_X0   0u               // float[NPTS*4]      1 MB
#define O_IDX  1048576u         // int[NPTS*20]       5 MB
#define O_X1   6291456u         // float[NPTS*64]     16 MB
#define O_UV   23068672u        // float[NPTS*256]    64 MB (knn packed partial lists overlay this)
#define O_WT   90177536u        // folded weights + out2enc + Wlh

// ---------------- helpers ----------------
__device__ __forceinline__ unsigned encf(float v) {
    unsigned u = __float_as_uint(v);
    return (u & 0x80000000u) ? ~u : (u | 0x80000000u);
}
__device__ __forceinline__ float decf(unsigned k) {
    unsigned u = (k & 0x80000000u) ? (k ^ 0x80000000u) : ~k;
    return __uint_as_float(u);
}
__device__ __forceinline__ unsigned ordf(float f) {
    unsigned u = __float_as_uint(f);
    return u ^ (((unsigned)((int)u >> 31)) | 0x80000000u);
}
// deterministic distance: identical instruction sequence at every use site
__device__ __forceinline__ float distf(float4 xi, float sqi, float4 xj, float sqj) {
    float dot = xi.x * xj.x;
    dot = fmaf(xi.y, xj.y, dot);
    dot = fmaf(xi.z, xj.z, dot);
    dot = fmaf(xi.w, xj.w, dot);
    return fmaf(-2.0f, dot, sqi + sqj);
}
__device__ __forceinline__ float fdot2f(h2 a, h2 b, float c) {
#if __has_builtin(__builtin_amdgcn_fdot2)
    return __builtin_amdgcn_fdot2(a, b, c, false);
#else
    return fmaf((float)a[0], (float)b[0], fmaf((float)a[1], (float)b[1], c));
#endif
}
// explicit umin/umax so InstCombine forms llvm.umin/umax -> v_min_u32/v_max_u32
__device__ __forceinline__ unsigned uminu(unsigned a, unsigned b) { return a < b ? a : b; }
__device__ __forceinline__ unsigned umaxu(unsigned a, unsigned b) { return a < b ? b : a; }

// 20-slot chain: w19 best (smallest) .. w0 = 20th smallest (tau)
#define TK_DECL unsigned w0=0xFFFFFFFFu,w1=0xFFFFFFFFu,w2=0xFFFFFFFFu,w3=0xFFFFFFFFu,w4=0xFFFFFFFFu, \
    w5=0xFFFFFFFFu,w6=0xFFFFFFFFu,w7=0xFFFFFFFFu,w8=0xFFFFFFFFu,w9=0xFFFFFFFFu, \
    w10=0xFFFFFFFFu,w11=0xFFFFFFFFu,w12=0xFFFFFFFFu,w13=0xFFFFFFFFu,w14=0xFFFFFFFFu, \
    w15=0xFFFFFFFFu,w16=0xFFFFFFFFu,w17=0xFFFFFFFFu,w18=0xFFFFFFFFu,w19=0xFFFFFFFFu;
#define TK_STEP(S) { unsigned mn = uminu(cu, S); cu = umaxu(cu, S); S = mn; }
#define TK_INSERT(uv_) { unsigned cu = (uv_); \
    TK_STEP(w19) TK_STEP(w18) TK_STEP(w17) TK_STEP(w16) TK_STEP(w15) \
    TK_STEP(w14) TK_STEP(w13) TK_STEP(w12) TK_STEP(w11) TK_STEP(w10) \
    TK_STEP(w9)  TK_STEP(w8)  TK_STEP(w7)  TK_STEP(w6)  TK_STEP(w5)  \
    TK_STEP(w4)  TK_STEP(w3)  TK_STEP(w2)  TK_STEP(w1)  TK_STEP(w0)  }

// ---------------- K0: fold BN into weights, build Wuv, zero pool accumulators ----------------
__global__ void k_fold(const float* __restrict__ W1, const float* __restrict__ b1,
                       const float* __restrict__ g1, const float* __restrict__ be1,
                       const float* __restrict__ m1, const float* __restrict__ v1,
                       const float* __restrict__ W2, const float* __restrict__ b2,
                       const float* __restrict__ g2, const float* __restrict__ be2,
                       const float* __restrict__ m2, const float* __restrict__ v2,
                       const float* __restrict__ Wc,
                       float* __restrict__ W1f, float* __restrict__ b1f,
                       float* __restrict__ W2f, float* __restrict__ b2f,
                       float* __restrict__ Wuv, unsigned* __restrict__ out2enc)
{
    int t = threadIdx.x;
    for (int i = t; i < 64; i += 256) {
        float s1 = g1[i] * rsqrtf(v1[i] + EPSBN);
        b1f[i] = (b1[i] - m1[i]) * s1 + be1[i];
        float s2 = g2[i] * rsqrtf(v2[i] + EPSBN);
        b2f[i] = (b2[i] - m2[i]) * s2 + be2[i];
    }
    for (int i = t; i < 8*64; i += 256) {
        int c = i & 63;
        W1f[i] = W1[i] * (g1[c] * rsqrtf(v1[c] + EPSBN));
    }
    for (int i = t; i < 64*64; i += 256) {
        int c = i & 63;
        W2f[i] = W2[i] * (g2[c] * rsqrtf(v2[c] + EPSBN));
    }
    for (int i = t; i < 64*256; i += 256) {
        int d = i >> 8, c = i & 255;
        Wuv[i] = (c < 128) ? (Wc[d*128 + c] - Wc[(64+d)*128 + c])
                           : Wc[(64+d)*128 + (c - 128)];
    }
    for (int i = t; i < 16*1024; i += 256) out2enc[i] = 0u;
}

// ---------------- K0b: x0 = [pos | feat] ----------------
__global__ void k_x0(const float* __restrict__ pos, const float* __restrict__ feat,
                     float* __restrict__ x0)
{
    int i = blockIdx.x*256 + threadIdx.x;
    if (i < NPTS) {
        float4 v;
        v.x = pos[i*3+0]; v.y = pos[i*3+1]; v.z = pos[i*3+2]; v.w = feat[i];
        ((float4*)x0)[i] = v;
    }
}

// ---------------- K0c: Wlh[j][k] = fp16(Wl[k][j])  (transpose, 32x32 LDS tiles) --------
__global__ __launch_bounds__(256) void k_wlh(const float* __restrict__ Wl, _Float16* __restrict__ Wlh)
{
    __shared__ float tile[32][33];
    int jb = blockIdx.x * 32, kb = blockIdx.y * 32;
    int tx = threadIdx.x & 31, ty = threadIdx.x >> 5;  // 8 rows per pass
    #pragma unroll
    for (int r = 0; r < 32; r += 8)
        tile[ty + r][tx] = Wl[(size_t)(kb + ty + r)*1024 + jb + tx];
    __syncthreads();
    #pragma unroll
    for (int r = 0; r < 32; r += 8)
        Wlh[(size_t)(jb + ty + r)*192 + kb + tx] = (_Float16)tile[tx][ty + r];
}

// ---------------- K1a: segmented kNN partials (u32 chain + single recovery pass) ----------
__global__ __launch_bounds__(256, 2) void k_knn_part(const float* __restrict__ x0,
        u64* __restrict__ pk)
{
    __shared__ float4 pts[1024];
    __shared__ float  sqs[1024];
    int x  = blockIdx.x;
    int b  = x >> 6;
    int rb = (x >> 2) & 15;
    int s  = x & 3;
    int t  = threadIdx.x;
    int r  = b*NPG + rb*256 + t;
    float4 xi = ((const float4*)x0)[r];
    float sqi = xi.x*xi.x + xi.y*xi.y + xi.z*xi.z + xi.w*xi.w;
    #pragma unroll
    for (int l = 0; l < 4; ++l) {
        float4 v = ((const float4*)x0)[b*NPG + s*1024 + l*256 + t];
        pts[l*256 + t] = v;
        sqs[l*256 + t] = v.x*v.x + v.y*v.y + v.z*v.z + v.w*v.w;
    }
    __syncthreads();

    TK_DECL
    for (int j = 0; j < 1024; ++j) {
        float d = distf(xi, sqi, pts[j], sqs[j]);
        unsigned u = ordf(d);
        TK_INSERT(u)
    }
    unsigned tauU = w0;   // 20th smallest (orderable u32) in this segment

    int jbase = b*NPG + s*1024;
    u64* pcol = pk + (size_t)s*KNN*NPTS + r;
    unsigned cnt = 0, ecnt = 0;
    int e0 = 0, e1 = 0;
    // single recovery pass: stricts stored directly (provably <= 19);
    // first two tau-equal indices kept in registers, appended after.
    #pragma unroll 1
    for (int j = 0; j < 1024; ++j) {
        float d = distf(xi, sqi, pts[j], sqs[j]);
        unsigned u = ordf(d);
        if (u < tauU) {
            pcol[(size_t)cnt*NPTS] = ((u64)u << 32) | (unsigned)(jbase + j);
            cnt++;
        } else if (u == tauU) {
            if (ecnt == 0) e0 = j; else if (ecnt == 1) e1 = j;
            ecnt++;
        }
    }
    if (cnt < KNN && ecnt > 0) { pcol[(size_t)cnt*NPTS] = ((u64)tauU << 32) | (unsigned)(jbase + e0); cnt++; }
    if (cnt < KNN && ecnt > 1) { pcol[(size_t)cnt*NPTS] = ((u64)tauU << 32) | (unsigned)(jbase + e1); cnt++; }
    // defensive fill (>=3-way bit-identical boundary tie only): +inf keys never win the merge
    while (cnt < KNN) {
        pcol[(size_t)cnt*NPTS] = ((u64)0xFFFFFFFFu << 32) | (unsigned)r;
        cnt++;
    }
}

// ---------------- K1b: merge 4 partial lists -> final 20 indices (set only) --------
__global__ __launch_bounds__(256, 2) void k_knn_merge(const u64* __restrict__ pk,
        int* __restrict__ idx)
{
    int r = blockIdx.x*256 + threadIdx.x;
    const unsigned* ph = (const unsigned*)pk;   // hi word (ordf value) of slot q

    TK_DECL
    #pragma unroll 4
    for (int q = 0; q < SEG*KNN; ++q) {
        unsigned u = ph[((size_t)q*NPTS + r)*2 + 1];
        TK_INSERT(u)
    }
    unsigned tauU = w0;

    unsigned cnt = 0;
    int* o = idx + (size_t)r*KNN;
    for (int q = 0; q < SEG*KNN; ++q) {
        u64 key = pk[(size_t)q*NPTS + r];
        unsigned u = (unsigned)(key >> 32);
        if (u < tauU && cnt < KNN) { o[cnt] = (int)(unsigned)key; cnt++; }
    }
    for (int q = 0; q < SEG*KNN; ++q) {
        u64 key = pk[(size_t)q*NPTS + r];
        unsigned u = (unsigned)(key >> 32);
        if (u == tauU && cnt < KNN) { o[cnt] = (int)(unsigned)key; cnt++; }
    }
    while (cnt < KNN) { o[cnt] = r; cnt++; }
}

// ---------------- K2: EdgeConv1, one wave per block, fp16 LDS staging + v_dot2 ----------------
#define PTS 16
__global__ __launch_bounds__(64) void k_conv1(const float* __restrict__ x0, const int* __restrict__ idx,
        const float* __restrict__ W1f, const float* __restrict__ b1f,
        const float* __restrict__ W2f, const float* __restrict__ b2f,
        const float* __restrict__ W3,  const float* __restrict__ b3,
        float* __restrict__ x1)
{
    __shared__ _Float16 hs0[20*64];
    __shared__ _Float16 hs1[20*64];
    int c = threadIdx.x;
    float w1c[8];
    h2 w2h[32], w3h[32];
    #pragma unroll
    for (int f = 0; f < 8; ++f)  w1c[f] = W1f[f*64 + c];
    #pragma unroll
    for (int m = 0; m < 32; ++m) {
        h2 a; a[0] = (_Float16)W2f[(2*m)*64 + c]; a[1] = (_Float16)W2f[(2*m+1)*64 + c];
        w2h[m] = a;
        h2 b; b[0] = (_Float16)W3[(2*m)*64 + c];  b[1] = (_Float16)W3[(2*m+1)*64 + c];
        w3h[m] = b;
    }
    float b1c = b1f[c], b2c = b2f[c], b3c = b3[c];

    #pragma unroll 1
    for (int pp = 0; pp < PTS; ++pp) {
        int i = blockIdx.x*PTS + pp;
        float4 xi = ((const float4*)x0)[i];
        #pragma unroll 4
        for (int k = 0; k < KNN; ++k) {
            int j = idx[i*KNN + k];
            float4 xj = ((const float4*)x0)[j];
            float h = b1c + xi.x*w1c[0] + xi.y*w1c[1] + xi.z*w1c[2] + xi.w*w1c[3]
                          + (xj.x-xi.x)*w1c[4] + (xj.y-xi.y)*w1c[5]
                          + (xj.z-xi.z)*w1c[6] + (xj.w-xi.w)*w1c[7];
            hs0[k*64 + c] = (_Float16)fmaxf(h, 0.0f);
        }
        __syncthreads();
        #pragma unroll 1
        for (int kc = 0; kc < 4; ++kc) {
            float acc[5];
            #pragma unroll
            for (int k5 = 0; k5 < 5; ++k5) acc[k5] = b2c;
            #pragma unroll
            for (int q = 0; q < 8; ++q) {
                #pragma unroll
                for (int k5 = 0; k5 < 5; ++k5) {
                    half8 hv = *(const half8*)&hs0[(kc*5 + k5)*64 + q*8];
                    acc[k5] = fdot2f(__builtin_shufflevector(hv, hv, 0, 1), w2h[q*4+0], acc[k5]);
                    acc[k5] = fdot2f(__builtin_shufflevector(hv, hv, 2, 3), w2h[q*4+1], acc[k5]);
                    acc[k5] = fdot2f(__builtin_shufflevector(hv, hv, 4, 5), w2h[q*4+2], acc[k5]);
                    acc[k5] = fdot2f(__builtin_shufflevector(hv, hv, 6, 7), w2h[q*4+3], acc[k5]);
                }
            }
            #pragma unroll
            for (int k5 = 0; k5 < 5; ++k5)
                hs1[(kc*5 + k5)*64 + c] = (_Float16)fmaxf(acc[k5], 0.0f);
        }
        __syncthreads();
        float mx = -3.0e38f;
        #pragma unroll 1
        for (int kc = 0; kc < 4; ++kc) {
            float acc[5];
            #pragma unroll
            for (int k5 = 0; k5 < 5; ++k5) acc[k5] = b3c;
            #pragma unroll
            for (int q = 0; q < 8; ++q) {
                #pragma unroll
                for (int k5 = 0; k5 < 5; ++k5) {
                    half8 hv = *(const half8*)&hs1[(kc*5 + k5)*64 + q*8];
                    acc[k5] = fdot2f(__builtin_shufflevector(hv, hv, 0, 1), w3h[q*4+0], acc[k5]);
                    acc[k5] = fdot2f(__builtin_shufflevector(hv, hv, 2, 3), w3h[q*4+1], acc[k5]);
                    acc[k5] = fdot2f(__builtin_shufflevector(hv, hv, 4, 5), w3h[q*4+2], acc[k5]);
                    acc[k5] = fdot2f(__builtin_shufflevector(hv, hv, 6, 7), w3h[q*4+3], acc[k5]);
                }
            }
            #pragma unroll
            for (int k5 = 0; k5 < 5; ++k5) mx = fmaxf(mx, acc[k5]);
        }
        x1[(size_t)i*64 + c] = mx;
        __syncthreads();
    }
}

// ---------------- K3: uv = x1 @ [Wu | Wv]  (u' gets +bc) ----------------
__global__ __launch_bounds__(256) void k_uv(const float* __restrict__ x1, const float* __restrict__ Wuv,
                                            const float* __restrict__ bc, float* __restrict__ uv)
{
    __shared__ float4 As[64*16];  // 64 rows x 64 cols of x1
    int m0 = blockIdx.x * 64;
    int t  = threadIdx.x;
    #pragma unroll
    for (int l = 0; l < 4; ++l) {
        int lin = l*256 + t;  // 0..1023
        As[lin] = ((const float4*)x1)[(size_t)m0*16 + lin];
    }
    __syncthreads();
    int c = t;  // 0..255
    float acc[64];
    #pragma unroll
    for (int p = 0; p < 64; ++p) acc[p] = 0.f;
    for (int dq = 0; dq < 16; ++dq) {
        float bv0 = Wuv[(dq*4+0)*256 + c];
        float bv1 = Wuv[(dq*4+1)*256 + c];
        float bv2 = Wuv[(dq*4+2)*256 + c];
        float bv3 = Wuv[(dq*4+3)*256 + c];
        #pragma unroll
        for (int p = 0; p < 64; ++p) {
            float4 a = As[p*16 + dq];
            acc[p] += a.x*bv0 + a.y*bv1 + a.z*bv2 + a.w*bv3;
        }
    }
    float badd = (c < 128) ? bc[c] : 0.0f;
    #pragma unroll
    for (int p = 0; p < 64; ++p)
        uv[(size_t)(m0+p)*256 + c] = acc[p] + badd;
}

// ---------------- K4: x2 = u' + max_k v[nbr]  (in-place into u' half of uv) ----------------
__global__ __launch_bounds__(256) void k_x2(const int* __restrict__ idx, float* __restrict__ uv)
{
    int p = blockIdx.x*2 + (threadIdx.x >> 7);
    int c = threadIdx.x & 127;
    float m = -3.0e38f;
    #pragma unroll
    for (int k = 0; k < KNN; ++k) {
        int j = idx[p*KNN + k];
        m = fmaxf(m, uv[(size_t)j*256 + 128 + c]);
    }
    uv[(size_t)p*256 + c] += m;
}

// ---------------- K5: out1 = [x1|x2] @ Wl (+bl) via fp16 MFMA, fused max-pool ------------
// grid (8 N-blocks, 1024 M-blocks), 256 threads (4 waves). Tile 64(M) x 128(N), K=192.
__global__ __launch_bounds__(256) void k_out1(const float* __restrict__ x1, const float* __restrict__ uv,
        const _Float16* __restrict__ Wlh, const float* __restrict__ bl, unsigned* __restrict__ out2enc)
{
    __shared__ _Float16 Asd[64][208];   // 416B row stride -> conflict-free b128 frags
    __shared__ _Float16 Bsd[128][208];
    int n0 = blockIdx.x * 128;
    int m0 = blockIdx.y * 64;
    int t  = threadIdx.x;

    // stage A: row = t>>2, cols [sub*48, sub*48+48): x1 (0..63) | x2=uv[...][0..127] (64..191)
    {
        int row = t >> 2, sub = t & 3;
        const float* xr = x1 + (size_t)(m0 + row)*64;
        const float* ur = uv + (size_t)(m0 + row)*256;
        #pragma unroll
        for (int cc = 0; cc < 12; ++cc) {
            int col = sub*48 + cc*4;
            float4 v = (col < 64) ? *(const float4*)(xr + col)
                                  : *(const float4*)(ur + (col - 64));
            h4 hv;
            hv[0] = (_Float16)v.x; hv[1] = (_Float16)v.y;
            hv[2] = (_Float16)v.z; hv[3] = (_Float16)v.w;
            *(h4*)&Asd[row][col] = hv;
        }
    }
    // stage B: Bsd[j][k] = Wlh[n0+j][k] (vector copies)
    {
        int j = t >> 1, hf = t & 1;
        const ushort8* src = (const ushort8*)(Wlh + (size_t)(n0 + j)*192 + hf*96);
        #pragma unroll
        for (int ch = 0; ch < 12; ++ch)
            *(ushort8*)&Bsd[j][hf*96 + ch*8] = src[ch];
    }
    __syncthreads();

    int w  = t >> 6, l = t & 63;
    int lr = l & 15, lg = l >> 4;
    f32x4 acc[8];
    #pragma unroll
    for (int f = 0; f < 8; ++f) acc[f] = (f32x4){0.f, 0.f, 0.f, 0.f};
    #pragma unroll 1
    for (int ks = 0; ks < 6; ++ks) {
        half8 a = *(const half8*)&Asd[w*16 + lr][ks*32 + lg*8];
        #pragma unroll
        for (int f = 0; f < 8; ++f) {
            half8 b = *(const half8*)&Bsd[f*16 + lr][ks*32 + lg*8];
            acc[f] = __builtin_amdgcn_mfma_f32_16x16x32_f16(a, b, acc[f], 0, 0, 0);
        }
    }
    // epilogue: max over the block's 64 rows per column, +bias, atomicMax
    float cmax[8];
    #pragma unroll
    for (int f = 0; f < 8; ++f) {
        float m = fmaxf(fmaxf(acc[f][0], acc[f][1]), fmaxf(acc[f][2], acc[f][3]));
        m = fmaxf(m, __shfl_xor(m, 16));
        m = fmaxf(m, __shfl_xor(m, 32));
        cmax[f] = m;   // lanes with equal lr now hold the wave's 16-row col-max
    }
    __syncthreads();                     // done reading Asd; reuse as reduction scratch
    float* red = (float*)&Asd[0][0];     // [4][128]
    if (l < 16) {
        #pragma unroll
        for (int f = 0; f < 8; ++f) red[w*128 + f*16 + l] = cmax[f];
    }
    __syncthreads();
    if (t < 128) {
        float m = fmaxf(fmaxf(red[t], red[128 + t]), fmaxf(red[256 + t], red[384 + t]));
        m += bl[n0 + t];
        int g = m0 >> 12;
        atomicMax(&out2enc[g*1024 + n0 + t], encf(m));
    }
}

// ---------------- K6: per-graph head MLP + log_softmax ----------------
__global__ __launch_bounds__(256) void k_head(const unsigned* __restrict__ out2enc,
        const float* __restrict__ Wa, const float* __restrict__ ba,
        const float* __restrict__ Wb, const float* __restrict__ bb,
        const float* __restrict__ Wo, const float* __restrict__ bo,
        float* __restrict__ out)
{
    __shared__ float s1[1024];
    __shared__ float s2[512];
    __shared__ float s3[256];
    __shared__ float sl[NC];
    int g = blockIdx.x, t = threadIdx.x;
    for (int i = t; i < 1024; i += 256) s1[i] = decf(out2enc[g*1024 + i]);
    __syncthreads();
    for (int cc = t; cc < 512; cc += 256) {
        float a = ba[cc];
        #pragma unroll 8
        for (int d = 0; d < 1024; ++d) a += s1[d] * Wa[(size_t)d*512 + cc];
        s2[cc] = fmaxf(a, 0.f);
    }
    __syncthreads();
    if (t < 256) {
        float a = bb[t];
        #pragma unroll 8
        for (int d = 0; d < 512; ++d) a += s2[d] * Wb[(size_t)d*256 + t];
        s3[t] = fmaxf(a, 0.f);
    }
    __syncthreads();
    if (t < NC) {
        float a = bo[t];
        #pragma unroll 8
        for (int d = 0; d < 256; ++d) a += s3[d] * Wo[d*NC + t];
        sl[t] = a;
    }
    __syncthreads();
    if (t < 64) {
        float v = (t < NC) ? sl[t] : -3.0e38f;
        float m = v;
        #pragma unroll
        for (int o2 = 32; o2 >= 1; o2 >>= 1) m = fmaxf(m, __shfl_xor(m, o2));
        float e = (t < NC) ? expf(sl[t] - m) : 0.f;
        float s = e;
        #pragma unroll
        for (int o2 = 32; o2 >= 1; o2 >>= 1) s += __shfl_xor(s, o2);
        float ls = logf(s) + m;
        if (t < NC) out[g*NC + t] = sl[t] - ls;
    }
}

// ---------------- launch ----------------
extern "C" void kernel_launch(void* const* d_in, const int* in_sizes, int n_in,
                              void* d_out, int out_size, void* d_ws, size_t ws_size,
                              hipStream_t stream)
{
    const float* pos  = (const float*)d_in[0];
    const float* feat = (const float*)d_in[1];
    const float* W1 = (const float*)d_in[2];
    const float* b1 = (const float*)d_in[3];
    const float* g1 = (const float*)d_in[4];
    const float* be1= (const float*)d_in[5];
    const float* m1 = (const float*)d_in[6];
    const float* v1 = (const float*)d_in[7];
    const float* W2 = (const float*)d_in[8];
    const float* b2 = (const float*)d_in[9];
    const float* g2 = (const float*)d_in[10];
    const float* be2= (const float*)d_in[11];
    const float* m2 = (const float*)d_in[12];
    const float* v2 = (const float*)d_in[13];
    const float* W3 = (const float*)d_in[14];
    const float* b3 = (const float*)d_in[15];
    const float* Wc = (const float*)d_in[16];
    const float* bc = (const float*)d_in[17];
    const float* Wl = (const float*)d_in[18];
    const float* bl = (const float*)d_in[19];
    const float* Wa = (const float*)d_in[20];
    const float* ba = (const float*)d_in[21];
    const float* Wb = (const float*)d_in[22];
    const float* bb = (const float*)d_in[23];
    const float* Wo = (const float*)d_in[24];
    const float* bo = (const float*)d_in[25];
    float* out = (float*)d_out;

    char* ws = (char*)d_ws;
    float* x0  = (float*)(ws + O_X0);
    int*   idx = (int*)  (ws + O_IDX);
    float* x1  = (float*)(ws + O_X1);
    float* uv  = (float*)(ws + O_UV);
    u64*   pk  = (u64*)  (ws + O_UV);   // packed knn partials overlay uv (dead until k_uv)
    float* W1f = (float*)(ws + O_WT);
    float* b1f = W1f + 512;
    float* W2f = b1f + 64;
    float* b2f = W2f + 4096;
    float* Wuv = b2f + 64;
    unsigned* out2enc = (unsigned*)(Wuv + 64*256);
    _Float16* Wlh = (_Float16*)(ws + O_WT + 262144);   // 1024x192 fp16 = 384 KB

    k_fold <<<1, 256, 0, stream>>>(W1,b1,g1,be1,m1,v1, W2,b2,g2,be2,m2,v2, Wc,
                                   W1f,b1f,W2f,b2f,Wuv,out2enc);
    k_x0   <<<NPTS/256, 256, 0, stream>>>(pos, feat, x0);
    dim3 gw(32, 6);
    k_wlh  <<<gw, 256, 0, stream>>>(Wl, Wlh);
    k_knn_part <<<BGRAPH*16*SEG, 256, 0, stream>>>(x0, pk);
    k_knn_merge<<<NPTS/256, 256, 0, stream>>>(pk, idx);
    k_conv1<<<NPTS/PTS, 64, 0, stream>>>(x0, idx, W1f, b1f, W2f, b2f, W3, b3, x1);
    k_uv   <<<NPTS/64, 256, 0, stream>>>(x1, Wuv, bc, uv);
    k_x2   <<<NPTS/2, 256, 0, stream>>>(idx, uv);
    dim3 g5(8, 1024);
    k_out1 <<<g5, 256, 0, stream>>>(x1, uv, Wlh, bl, out2enc);
    k_head <<<BGRAPH, 256, 0, stream>>>(out2enc, Wa,ba,Wb,bb,Wo,bo, out);
}

// Round 9
// 1122.550 us; speedup vs baseline: 3.6128x; 1.1744x over previous
//
#include <hip/hip_runtime.h>
#include <math.h>

#define BGRAPH 16
#define NPG    4096
#define NPTS   (BGRAPH*NPG)   // 65536
#define KNN    20
#define NC     40
#define EPSBN  1e-5f
#define SEG    4

typedef _Float16 half8 __attribute__((ext_vector_type(8)));
typedef _Float16 h4 __attribute__((ext_vector_type(4)));
typedef _Float16 h2 __attribute__((ext_vector_type(2)));
typedef unsigned short ushort8 __attribute__((ext_vector_type(8)));
typedef float f32x4 __attribute__((ext_vector_type(4)));
typedef unsigned long long u64;

// ---------------- ws layout (bytes) ----------------
#define O_X0   0u               // float[NPTS*4]      1 MB
#define O_IDX  1048576u         // int[NPTS*20]       5 MB
#define O_X1   6291456u         // float[NPTS*64]     16 MB
#define O_UV   23068672u        // float[NPTS*256]    64 MB (knn packed partial lists overlay this)
#define O_WT   90177536u        // folded weights + out2enc + Wlh + s2g

// ---------------- helpers ----------------
__device__ __forceinline__ unsigned encf(float v) {
    unsigned u = __float_as_uint(v);
    return (u & 0x80000000u) ? ~u : (u | 0x80000000u);
}
__device__ __forceinline__ float decf(unsigned k) {
    unsigned u = (k & 0x80000000u) ? (k ^ 0x80000000u) : ~k;
    return __uint_as_float(u);
}
__device__ __forceinline__ unsigned ordf(float f) {
    unsigned u = __float_as_uint(f);
    return u ^ (((unsigned)((int)u >> 31)) | 0x80000000u);
}
// deterministic distance: identical instruction sequence at every use site
__device__ __forceinline__ float distf(float4 xi, float sqi, float4 xj, float sqj) {
    float dot = xi.x * xj.x;
    dot = fmaf(xi.y, xj.y, dot);
    dot = fmaf(xi.z, xj.z, dot);
    dot = fmaf(xi.w, xj.w, dot);
    return fmaf(-2.0f, dot, sqi + sqj);
}
__device__ __forceinline__ float fdot2f(h2 a, h2 b, float c) {
#if __has_builtin(__builtin_amdgcn_fdot2)
    return __builtin_amdgcn_fdot2(a, b, c, false);
#else
    return fmaf((float)a[0], (float)b[0], fmaf((float)a[1], (float)b[1], c));
#endif
}
__device__ __forceinline__ unsigned uminu(unsigned a, unsigned b) { return a < b ? a : b; }
// hardware 3-input median (exact sorted-insert primitive)
__device__ __forceinline__ unsigned umed3(unsigned a, unsigned b, unsigned c) {
    unsigned d;
    asm("v_med3_u32 %0, %1, %2, %3" : "=v"(d) : "v"(a), "v"(b), "v"(c));
    return d;
}

// 20-slot chain: w19 best (smallest) .. w0 = 20th smallest (tau).
// med3 insertion: w_i' = med3(w_{i+1}, w_i, c) (uses OLD values, depth-1), w19' = min(w19, c).
// Exactly equivalent to the compare-exchange bubble insert, at half the ops.
#define TK_DECL unsigned w0=0xFFFFFFFFu,w1=0xFFFFFFFFu,w2=0xFFFFFFFFu,w3=0xFFFFFFFFu,w4=0xFFFFFFFFu, \
    w5=0xFFFFFFFFu,w6=0xFFFFFFFFu,w7=0xFFFFFFFFu,w8=0xFFFFFFFFu,w9=0xFFFFFFFFu, \
    w10=0xFFFFFFFFu,w11=0xFFFFFFFFu,w12=0xFFFFFFFFu,w13=0xFFFFFFFFu,w14=0xFFFFFFFFu, \
    w15=0xFFFFFFFFu,w16=0xFFFFFFFFu,w17=0xFFFFFFFFu,w18=0xFFFFFFFFu,w19=0xFFFFFFFFu;
#define TK_INSERT(uv_) { unsigned cu = (uv_); \
    w0  = umed3(w1,  w0,  cu); \
    w1  = umed3(w2,  w1,  cu); \
    w2  = umed3(w3,  w2,  cu); \
    w3  = umed3(w4,  w3,  cu); \
    w4  = umed3(w5,  w4,  cu); \
    w5  = umed3(w6,  w5,  cu); \
    w6  = umed3(w7,  w6,  cu); \
    w7  = umed3(w8,  w7,  cu); \
    w8  = umed3(w9,  w8,  cu); \
    w9  = umed3(w10, w9,  cu); \
    w10 = umed3(w11, w10, cu); \
    w11 = umed3(w12, w11, cu); \
    w12 = umed3(w13, w12, cu); \
    w13 = umed3(w14, w13, cu); \
    w14 = umed3(w15, w14, cu); \
    w15 = umed3(w16, w15, cu); \
    w16 = umed3(w17, w16, cu); \
    w17 = umed3(w18, w17, cu); \
    w18 = umed3(w19, w18, cu); \
    w19 = uminu(w19, cu); }

// ---------------- K_prep: fused x0-build + Wl transpose + BN fold (independent jobs) -----
__global__ __launch_bounds__(256) void k_prep(
        const float* __restrict__ pos, const float* __restrict__ feat,
        const float* __restrict__ Wl,
        const float* __restrict__ W1, const float* __restrict__ b1,
        const float* __restrict__ g1, const float* __restrict__ be1,
        const float* __restrict__ m1, const float* __restrict__ v1,
        const float* __restrict__ W2, const float* __restrict__ b2,
        const float* __restrict__ g2, const float* __restrict__ be2,
        const float* __restrict__ m2, const float* __restrict__ v2,
        const float* __restrict__ Wc,
        float* __restrict__ x0, _Float16* __restrict__ Wlh,
        float* __restrict__ W1f, float* __restrict__ b1f,
        float* __restrict__ W2f, float* __restrict__ b2f,
        float* __restrict__ Wuv, unsigned* __restrict__ out2enc)
{
    __shared__ float tile[32][33];
    int bx = blockIdx.x, t = threadIdx.x;
    if (bx < 256) {                       // x0 = [pos | feat]
        int i = bx*256 + t;
        float4 v;
        v.x = pos[i*3+0]; v.y = pos[i*3+1]; v.z = pos[i*3+2]; v.w = feat[i];
        ((float4*)x0)[i] = v;
    } else if (bx < 256 + 192) {          // Wlh[j][k] = fp16(Wl[k][j])
        int w = bx - 256;
        int jb = (w & 31) * 32, kb = (w >> 5) * 32;
        int tx = t & 31, ty = t >> 5;
        #pragma unroll
        for (int r = 0; r < 32; r += 8)
            tile[ty + r][tx] = Wl[(size_t)(kb + ty + r)*1024 + jb + tx];
        __syncthreads();
        #pragma unroll
        for (int r = 0; r < 32; r += 8)
            Wlh[(size_t)(jb + ty + r)*192 + kb + tx] = (_Float16)tile[tx][ty + r];
    } else {                              // BN fold + Wuv + pool-accumulator zero
        for (int i = t; i < 64; i += 256) {
            float s1 = g1[i] * rsqrtf(v1[i] + EPSBN);
            b1f[i] = (b1[i] - m1[i]) * s1 + be1[i];
            float s2 = g2[i] * rsqrtf(v2[i] + EPSBN);
            b2f[i] = (b2[i] - m2[i]) * s2 + be2[i];
        }
        for (int i = t; i < 8*64; i += 256) {
            int c = i & 63;
            W1f[i] = W1[i] * (g1[c] * rsqrtf(v1[c] + EPSBN));
        }
        for (int i = t; i < 64*64; i += 256) {
            int c = i & 63;
            W2f[i] = W2[i] * (g2[c] * rsqrtf(v2[c] + EPSBN));
        }
        for (int i = t; i < 64*256; i += 256) {
            int d = i >> 8, c = i & 255;
            Wuv[i] = (c < 128) ? (Wc[d*128 + c] - Wc[(64+d)*128 + c])
                               : Wc[(64+d)*128 + (c - 128)];
        }
        for (int i = t; i < 16*1024; i += 256) out2enc[i] = 0u;
    }
}

// ---------------- K1a: segmented kNN partials (med3 chain + single recovery pass) --------
__global__ __launch_bounds__(256, 2) void k_knn_part(const float* __restrict__ x0,
        u64* __restrict__ pk)
{
    __shared__ float4 pts[1024];
    __shared__ float  sqs[1024];
    int x  = blockIdx.x;
    int b  = x >> 6;
    int rb = (x >> 2) & 15;
    int s  = x & 3;
    int t  = threadIdx.x;
    int r  = b*NPG + rb*256 + t;
    float4 xi = ((const float4*)x0)[r];
    float sqi = xi.x*xi.x + xi.y*xi.y + xi.z*xi.z + xi.w*xi.w;
    #pragma unroll
    for (int l = 0; l < 4; ++l) {
        float4 v = ((const float4*)x0)[b*NPG + s*1024 + l*256 + t];
        pts[l*256 + t] = v;
        sqs[l*256 + t] = v.x*v.x + v.y*v.y + v.z*v.z + v.w*v.w;
    }
    __syncthreads();

    TK_DECL
    for (int j = 0; j < 1024; ++j) {
        float d = distf(xi, sqi, pts[j], sqs[j]);
        unsigned u = ordf(d);
        TK_INSERT(u)
    }
    unsigned tauU = w0;   // 20th smallest (orderable u32) in this segment

    int jbase = b*NPG + s*1024;
    u64* pcol = pk + (size_t)s*KNN*NPTS + r;
    unsigned cnt = 0, ecnt = 0;
    int e0 = 0, e1 = 0;
    // single recovery pass: stricts stored directly (provably <= 19);
    // first two tau-equal indices kept in registers, appended after.
    #pragma unroll 1
    for (int j = 0; j < 1024; ++j) {
        float d = distf(xi, sqi, pts[j], sqs[j]);
        unsigned u = ordf(d);
        if (u < tauU) {
            pcol[(size_t)cnt*NPTS] = ((u64)u << 32) | (unsigned)(jbase + j);
            cnt++;
        } else if (u == tauU) {
            if (ecnt == 0) e0 = j; else if (ecnt == 1) e1 = j;
            ecnt++;
        }
    }
    if (cnt < KNN && ecnt > 0) { pcol[(size_t)cnt*NPTS] = ((u64)tauU << 32) | (unsigned)(jbase + e0); cnt++; }
    if (cnt < KNN && ecnt > 1) { pcol[(size_t)cnt*NPTS] = ((u64)tauU << 32) | (unsigned)(jbase + e1); cnt++; }
    // defensive fill (>=3-way bit-identical boundary tie only): +inf keys never win the merge
    while (cnt < KNN) {
        pcol[(size_t)cnt*NPTS] = ((u64)0xFFFFFFFFu << 32) | (unsigned)r;
        cnt++;
    }
}

// ---------------- K1b: merge 4 partial lists -> final 20 indices (set only) --------
__global__ __launch_bounds__(256, 2) void k_knn_merge(const u64* __restrict__ pk,
        int* __restrict__ idx)
{
    int r = blockIdx.x*256 + threadIdx.x;
    const unsigned* ph = (const unsigned*)pk;   // hi word (ordf value) of slot q

    TK_DECL
    #pragma unroll 4
    for (int q = 0; q < SEG*KNN; ++q) {
        unsigned u = ph[((size_t)q*NPTS + r)*2 + 1];
        TK_INSERT(u)
    }
    unsigned tauU = w0;

    unsigned cnt = 0;
    int* o = idx + (size_t)r*KNN;
    for (int q = 0; q < SEG*KNN; ++q) {
        u64 key = pk[(size_t)q*NPTS + r];
        unsigned u = (unsigned)(key >> 32);
        if (u < tauU && cnt < KNN) { o[cnt] = (int)(unsigned)key; cnt++; }
    }
    for (int q = 0; q < SEG*KNN; ++q) {
        u64 key = pk[(size_t)q*NPTS + r];
        unsigned u = (unsigned)(key >> 32);
        if (u == tauU && cnt < KNN) { o[cnt] = (int)(unsigned)key; cnt++; }
    }
    while (cnt < KNN) { o[cnt] = r; cnt++; }
}

// ---------------- K2: EdgeConv1, one wave per block, fp16 LDS staging + v_dot2 ----------------
#define PTS 16
__global__ __launch_bounds__(64) void k_conv1(const float* __restrict__ x0, const int* __restrict__ idx,
        const float* __restrict__ W1f, const float* __restrict__ b1f,
        const float* __restrict__ W2f, const float* __restrict__ b2f,
        const float* __restrict__ W3,  const float* __restrict__ b3,
        float* __restrict__ x1)
{
    __shared__ _Float16 hs0[20*64];
    __shared__ _Float16 hs1[20*64];
    int c = threadIdx.x;
    float w1c[8];
    h2 w2h[32], w3h[32];
    #pragma unroll
    for (int f = 0; f < 8; ++f)  w1c[f] = W1f[f*64 + c];
    #pragma unroll
    for (int m = 0; m < 32; ++m) {
        h2 a; a[0] = (_Float16)W2f[(2*m)*64 + c]; a[1] = (_Float16)W2f[(2*m+1)*64 + c];
        w2h[m] = a;
        h2 b; b[0] = (_Float16)W3[(2*m)*64 + c];  b[1] = (_Float16)W3[(2*m+1)*64 + c];
        w3h[m] = b;
    }
    float b1c = b1f[c], b2c = b2f[c], b3c = b3[c];

    #pragma unroll 1
    for (int pp = 0; pp < PTS; ++pp) {
        int i = blockIdx.x*PTS + pp;
        float4 xi = ((const float4*)x0)[i];
        #pragma unroll 4
        for (int k = 0; k < KNN; ++k) {
            int j = idx[i*KNN + k];
            float4 xj = ((const float4*)x0)[j];
            float h = b1c + xi.x*w1c[0] + xi.y*w1c[1] + xi.z*w1c[2] + xi.w*w1c[3]
                          + (xj.x-xi.x)*w1c[4] + (xj.y-xi.y)*w1c[5]
                          + (xj.z-xi.z)*w1c[6] + (xj.w-xi.w)*w1c[7];
            hs0[k*64 + c] = (_Float16)fmaxf(h, 0.0f);
        }
        __syncthreads();
        #pragma unroll 1
        for (int kc = 0; kc < 4; ++kc) {
            float acc[5];
            #pragma unroll
            for (int k5 = 0; k5 < 5; ++k5) acc[k5] = b2c;
            #pragma unroll
            for (int q = 0; q < 8; ++q) {
                #pragma unroll
                for (int k5 = 0; k5 < 5; ++k5) {
                    half8 hv = *(const half8*)&hs0[(kc*5 + k5)*64 + q*8];
                    acc[k5] = fdot2f(__builtin_shufflevector(hv, hv, 0, 1), w2h[q*4+0], acc[k5]);
                    acc[k5] = fdot2f(__builtin_shufflevector(hv, hv, 2, 3), w2h[q*4+1], acc[k5]);
                    acc[k5] = fdot2f(__builtin_shufflevector(hv, hv, 4, 5), w2h[q*4+2], acc[k5]);
                    acc[k5] = fdot2f(__builtin_shufflevector(hv, hv, 6, 7), w2h[q*4+3], acc[k5]);
                }
            }
            #pragma unroll
            for (int k5 = 0; k5 < 5; ++k5)
                hs1[(kc*5 + k5)*64 + c] = (_Float16)fmaxf(acc[k5], 0.0f);
        }
        __syncthreads();
        float mx = -3.0e38f;
        #pragma unroll 1
        for (int kc = 0; kc < 4; ++kc) {
            float acc[5];
            #pragma unroll
            for (int k5 = 0; k5 < 5; ++k5) acc[k5] = b3c;
            #pragma unroll
            for (int q = 0; q < 8; ++q) {
                #pragma unroll
                for (int k5 = 0; k5 < 5; ++k5) {
                    half8 hv = *(const half8*)&hs1[(kc*5 + k5)*64 + q*8];
                    acc[k5] = fdot2f(__builtin_shufflevector(hv, hv, 0, 1), w3h[q*4+0], acc[k5]);
                    acc[k5] = fdot2f(__builtin_shufflevector(hv, hv, 2, 3), w3h[q*4+1], acc[k5]);
                    acc[k5] = fdot2f(__builtin_shufflevector(hv, hv, 4, 5), w3h[q*4+2], acc[k5]);
                    acc[k5] = fdot2f(__builtin_shufflevector(hv, hv, 6, 7), w3h[q*4+3], acc[k5]);
                }
            }
            #pragma unroll
            for (int k5 = 0; k5 < 5; ++k5) mx = fmaxf(mx, acc[k5]);
        }
        x1[(size_t)i*64 + c] = mx;
        __syncthreads();
    }
}

// ---------------- K3: uv = x1 @ [Wu | Wv]  (u' gets +bc) ----------------
__global__ __launch_bounds__(256) void k_uv(const float* __restrict__ x1, const float* __restrict__ Wuv,
                                            const float* __restrict__ bc, float* __restrict__ uv)
{
    __shared__ float4 As[64*16];  // 64 rows x 64 cols of x1
    int m0 = blockIdx.x * 64;
    int t  = threadIdx.x;
    #pragma unroll
    for (int l = 0; l < 4; ++l) {
        int lin = l*256 + t;  // 0..1023
        As[lin] = ((const float4*)x1)[(size_t)m0*16 + lin];
    }
    __syncthreads();
    int c = t;  // 0..255
    float acc[64];
    #pragma unroll
    for (int p = 0; p < 64; ++p) acc[p] = 0.f;
    for (int dq = 0; dq < 16; ++dq) {
        float bv0 = Wuv[(dq*4+0)*256 + c];
        float bv1 = Wuv[(dq*4+1)*256 + c];
        float bv2 = Wuv[(dq*4+2)*256 + c];
        float bv3 = Wuv[(dq*4+3)*256 + c];
        #pragma unroll
        for (int p = 0; p < 64; ++p) {
            float4 a = As[p*16 + dq];
            acc[p] += a.x*bv0 + a.y*bv1 + a.z*bv2 + a.w*bv3;
        }
    }
    float badd = (c < 128) ? bc[c] : 0.0f;
    #pragma unroll
    for (int p = 0; p < 64; ++p)
        uv[(size_t)(m0+p)*256 + c] = acc[p] + badd;
}

// ---------------- K4: x2 = u' + max_k v[nbr]  (in-place into u' half of uv) ----------------
__global__ __launch_bounds__(256) void k_x2(const int* __restrict__ idx, float* __restrict__ uv)
{
    int p = blockIdx.x*2 + (threadIdx.x >> 7);
    int c = threadIdx.x & 127;
    float m = -3.0e38f;
    #pragma unroll
    for (int k = 0; k < KNN; ++k) {
        int j = idx[p*KNN + k];
        m = fmaxf(m, uv[(size_t)j*256 + 128 + c]);
    }
    uv[(size_t)p*256 + c] += m;
}

// ---------------- K5: out1 = [x1|x2] @ Wl (+bl) via fp16 MFMA, fused max-pool ------------
// grid (8 N-blocks, 1024 M-blocks), 256 threads (4 waves). Tile 64(M) x 128(N), K=192.
__global__ __launch_bounds__(256) void k_out1(const float* __restrict__ x1, const float* __restrict__ uv,
        const _Float16* __restrict__ Wlh, const float* __restrict__ bl, unsigned* __restrict__ out2enc)
{
    __shared__ _Float16 Asd[64][208];   // 416B row stride -> conflict-free b128 frags
    __shared__ _Float16 Bsd[128][208];
    int n0 = blockIdx.x * 128;
    int m0 = blockIdx.y * 64;
    int t  = threadIdx.x;

    // stage A: row = t>>2, cols [sub*48, sub*48+48): x1 (0..63) | x2=uv[...][0..127] (64..191)
    {
        int row = t >> 2, sub = t & 3;
        const float* xr = x1 + (size_t)(m0 + row)*64;
        const float* ur = uv + (size_t)(m0 + row)*256;
        #pragma unroll
        for (int cc = 0; cc < 12; ++cc) {
            int col = sub*48 + cc*4;
            float4 v = (col < 64) ? *(const float4*)(xr + col)
                                  : *(const float4*)(ur + (col - 64));
            h4 hv;
            hv[0] = (_Float16)v.x; hv[1] = (_Float16)v.y;
            hv[2] = (_Float16)v.z; hv[3] = (_Float16)v.w;
            *(h4*)&Asd[row][col] = hv;
        }
    }
    // stage B: Bsd[j][k] = Wlh[n0+j][k] (vector copies)
    {
        int j = t >> 1, hf = t & 1;
        const ushort8* src = (const ushort8*)(Wlh + (size_t)(n0 + j)*192 + hf*96);
        #pragma unroll
        for (int ch = 0; ch < 12; ++ch)
            *(ushort8*)&Bsd[j][hf*96 + ch*8] = src[ch];
    }
    __syncthreads();

    int w  = t >> 6, l = t & 63;
    int lr = l & 15, lg = l >> 4;
    f32x4 acc[8];
    #pragma unroll
    for (int f = 0; f < 8; ++f) acc[f] = (f32x4){0.f, 0.f, 0.f, 0.f};
    #pragma unroll 1
    for (int ks = 0; ks < 6; ++ks) {
        half8 a = *(const half8*)&Asd[w*16 + lr][ks*32 + lg*8];
        #pragma unroll
        for (int f = 0; f < 8; ++f) {
            half8 b = *(const half8*)&Bsd[f*16 + lr][ks*32 + lg*8];
            acc[f] = __builtin_amdgcn_mfma_f32_16x16x32_f16(a, b, acc[f], 0, 0, 0);
        }
    }
    // epilogue: max over the block's 64 rows per column, +bias, atomicMax
    float cmax[8];
    #pragma unroll
    for (int f = 0; f < 8; ++f) {
        float m = fmaxf(fmaxf(acc[f][0], acc[f][1]), fmaxf(acc[f][2], acc[f][3]));
        m = fmaxf(m, __shfl_xor(m, 16));
        m = fmaxf(m, __shfl_xor(m, 32));
        cmax[f] = m;   // lanes with equal lr now hold the wave's 16-row col-max
    }
    __syncthreads();                     // done reading Asd; reuse as reduction scratch
    float* red = (float*)&Asd[0][0];     // [4][128]
    if (l < 16) {
        #pragma unroll
        for (int f = 0; f < 8; ++f) red[w*128 + f*16 + l] = cmax[f];
    }
    __syncthreads();
    if (t < 128) {
        float m = fmaxf(fmaxf(red[t], red[128 + t]), fmaxf(red[256 + t], red[384 + t]));
        m += bl[n0 + t];
        int g = m0 >> 12;
        atomicMax(&out2enc[g*1024 + n0 + t], encf(m));
    }
}

// ---------------- K6a: head layer A (s2 = relu(out2 @ Wa + ba)), 32 blocks ----------------
__global__ __launch_bounds__(256) void k_headA(const unsigned* __restrict__ out2enc,
        const float* __restrict__ Wa, const float* __restrict__ ba, float* __restrict__ s2g)
{
    __shared__ float s1[1024];
    int g = blockIdx.x >> 1, half = blockIdx.x & 1;
    int t = threadIdx.x;
    for (int i = t; i < 1024; i += 256) s1[i] = decf(out2enc[g*1024 + i]);
    __syncthreads();
    int col = half*256 + t;
    float a0 = 0.f, a1 = 0.f, a2 = 0.f, a3 = 0.f;
    #pragma unroll 4
    for (int d = 0; d < 1024; d += 4) {
        a0 = fmaf(s1[d+0], Wa[(size_t)(d+0)*512 + col], a0);
        a1 = fmaf(s1[d+1], Wa[(size_t)(d+1)*512 + col], a1);
        a2 = fmaf(s1[d+2], Wa[(size_t)(d+2)*512 + col], a2);
        a3 = fmaf(s1[d+3], Wa[(size_t)(d+3)*512 + col], a3);
    }
    s2g[g*512 + col] = fmaxf(ba[col] + ((a0 + a1) + (a2 + a3)), 0.f);
}

// ---------------- K6b: head layers B/O + log_softmax, 16 blocks ----------------
__global__ __launch_bounds__(256) void k_headB(const float* __restrict__ s2g,
        const float* __restrict__ Wb, const float* __restrict__ bb,
        const float* __restrict__ Wo, const float* __restrict__ bo,
        float* __restrict__ out)
{
    __shared__ float s2[512];
    __shared__ float s3[256];
    __shared__ float sl[NC];
    int g = blockIdx.x, t = threadIdx.x;
    for (int i = t; i < 512; i += 256) s2[i] = s2g[g*512 + i];
    __syncthreads();
    {
        float a = bb[t];
        #pragma unroll 8
        for (int d = 0; d < 512; ++d) a += s2[d] * Wb[(size_t)d*256 + t];
        s3[t] = fmaxf(a, 0.f);
    }
    __syncthreads();
    if (t < NC) {
        float a = bo[t];
        #pragma unroll 8
        for (int d = 0; d < 256; ++d) a += s3[d] * Wo[d*NC + t];
        sl[t] = a;
    }
    __syncthreads();
    if (t < 64) {
        float v = (t < NC) ? sl[t] : -3.0e38f;
        float m = v;
        #pragma unroll
        for (int o2 = 32; o2 >= 1; o2 >>= 1) m = fmaxf(m, __shfl_xor(m, o2));
        float e = (t < NC) ? expf(sl[t] - m) : 0.f;
        float s = e;
        #pragma unroll
        for (int o2 = 32; o2 >= 1; o2 >>= 1) s += __shfl_xor(s, o2);
        float ls = logf(s) + m;
        if (t < NC) out[g*NC + t] = sl[t] - ls;
    }
}

// ---------------- launch ----------------
extern "C" void kernel_launch(void* const* d_in, const int* in_sizes, int n_in,
                              void* d_out, int out_size, void* d_ws, size_t ws_size,
                              hipStream_t stream)
{
    const float* pos  = (const float*)d_in[0];
    const float* feat = (const float*)d_in[1];
    const float* W1 = (const float*)d_in[2];
    const float* b1 = (const float*)d_in[3];
    const float* g1 = (const float*)d_in[4];
    const float* be1= (const float*)d_in[5];
    const float* m1 = (const float*)d_in[6];
    const float* v1 = (const float*)d_in[7];
    const float* W2 = (const float*)d_in[8];
    const float* b2 = (const float*)d_in[9];
    const float* g2 = (const float*)d_in[10];
    const float* be2= (const float*)d_in[11];
    const float* m2 = (const float*)d_in[12];
    const float* v2 = (const float*)d_in[13];
    const float* W3 = (const float*)d_in[14];
    const float* b3 = (const float*)d_in[15];
    const float* Wc = (const float*)d_in[16];
    const float* bc = (const float*)d_in[17];
    const float* Wl = (const float*)d_in[18];
    const float* bl = (const float*)d_in[19];
    const float* Wa = (const float*)d_in[20];
    const float* ba = (const float*)d_in[21];
    const float* Wb = (const float*)d_in[22];
    const float* bb = (const float*)d_in[23];
    const float* Wo = (const float*)d_in[24];
    const float* bo = (const float*)d_in[25];
    float* out = (float*)d_out;

    char* ws = (char*)d_ws;
    float* x0  = (float*)(ws + O_X0);
    int*   idx = (int*)  (ws + O_IDX);
    float* x1  = (float*)(ws + O_X1);
    float* uv  = (float*)(ws + O_UV);
    u64*   pk  = (u64*)  (ws + O_UV);   // packed knn partials overlay uv (dead until k_uv)
    float* W1f = (float*)(ws + O_WT);
    float* b1f = W1f + 512;
    float* W2f = b1f + 64;
    float* b2f = W2f + 4096;
    float* Wuv = b2f + 64;
    unsigned* out2enc = (unsigned*)(Wuv + 64*256);
    _Float16* Wlh = (_Float16*)(ws + O_WT + 262144);        // 1024x192 fp16 = 384 KB
    float* s2g = (float*)(ws + O_WT + 262144 + 393216);     // 16x512 f32 = 32 KB

    k_prep <<<449, 256, 0, stream>>>(pos, feat, Wl,
                                     W1,b1,g1,be1,m1,v1, W2,b2,g2,be2,m2,v2, Wc,
                                     x0, Wlh, W1f,b1f,W2f,b2f,Wuv,out2enc);
    k_knn_part <<<BGRAPH*16*SEG, 256, 0, stream>>>(x0, pk);
    k_knn_merge<<<NPTS/256, 256, 0, stream>>>(pk, idx);
    k_conv1<<<NPTS/PTS, 64, 0, stream>>>(x0, idx, W1f, b1f, W2f, b2f, W3, b3, x1);
    k_uv   <<<NPTS/64, 256, 0, stream>>>(x1, Wuv, bc, uv);
    k_x2   <<<NPTS/2, 256, 0, stream>>>(idx, uv);
    dim3 g5(8, 1024);
    k_out1 <<<g5, 256, 0, stream>>>(x1, uv, Wlh, bl, out2enc);
    k_headA<<<BGRAPH*2, 256, 0, stream>>>(out2enc, Wa, ba, s2g);
    k_headB<<<BGRAPH, 256, 0, stream>>>(s2g, Wb, bb, Wo, bo, out);
}